// Round 1
// baseline (631.135 us; speedup 1.0000x reference)
//
#include <hip/hip_runtime.h>
#include <math.h>

#define BB 2
#define CC 256
#define CI 128
#define NN 8192
#define MM 2048

// ws layout (float offsets)
#define OFF_THETA 0u
#define OFF_PHIP  2097152u   // 2*128*8192
#define OFF_GP    2621440u   // +2*128*2048
#define OFF_Y     3145728u   // +2*128*2048
#define OFF_PSUM  5242880u   // +2*128*8192
#define OFF_PSQ   5275648u   // +256*128
#define OFF_STAT  5308416u   // +256*128  (stats: mean[256], inv_std[256])

// ---------------------------------------------------------------------------
// Shared fp32 GEMM core: Out[64 o][128 n] = W[64][CIN] * X[CIN][NN]-tile
// thread layout: tx = tid&15 (8 n each), ty = tid>>4 (4 o each)
// ---------------------------------------------------------------------------
template<int CIN>
__device__ __forceinline__ void gemm_core(const float* __restrict__ Wm,   // pre-offset to obase row
                                          const float* __restrict__ X,   // pre-offset to batch
                                          int nbase, float (&acc)[4][8],
                                          float* __restrict__ Ws,        // [64*17]
                                          float* __restrict__ Xs)        // [16*132]
{
    const int tid = threadIdx.x;
    const int tx = tid & 15, ty = tid >> 4;
#pragma unroll
    for (int i = 0; i < 4; ++i)
#pragma unroll
        for (int j = 0; j < 8; ++j) acc[i][j] = 0.f;

    for (int c0 = 0; c0 < CIN; c0 += 16) {
        __syncthreads();   // protect previous iteration's reads
        for (int idx = tid; idx < 1024; idx += 256) {
            const int o = idx >> 4, kk = idx & 15;
            Ws[o * 17 + kk] = Wm[o * CIN + c0 + kk];
        }
        for (int idx = tid; idx < 512; idx += 256) {
            const int kk = idx >> 5, n4 = (idx & 31) << 2;
            *(float4*)&Xs[kk * 132 + n4] =
                *(const float4*)&X[(size_t)(c0 + kk) * NN + nbase + n4];
        }
        __syncthreads();
#pragma unroll
        for (int kk = 0; kk < 16; ++kk) {
            float xv[8], wv[4];
            *(float4*)&xv[0] = *(const float4*)&Xs[kk * 132 + tx * 8];
            *(float4*)&xv[4] = *(const float4*)&Xs[kk * 132 + tx * 8 + 4];
#pragma unroll
            for (int i = 0; i < 4; ++i) wv[i] = Ws[(ty * 4 + i) * 17 + kk];
#pragma unroll
            for (int i = 0; i < 4; ++i)
#pragma unroll
                for (int j = 0; j < 8; ++j)
                    acc[i][j] = fmaf(wv[i], xv[j], acc[i][j]);
        }
    }
}

// ---------------------------------------------------------------------------
// K1: theta/phi/g 1x1 convs; phi & g get 2x2 spatial max-pool
// grid: (64 ntiles, 6 otiles, 2 b). otile>>1: 0=theta,1=phi,2=g
// ---------------------------------------------------------------------------
__global__ __launch_bounds__(256) void k_qkv(
    const float* __restrict__ x,
    const float* __restrict__ tw, const float* __restrict__ tb,
    const float* __restrict__ pw, const float* __restrict__ pb,
    const float* __restrict__ gw, const float* __restrict__ gb,
    float* __restrict__ theta, float* __restrict__ phip, float* __restrict__ gp)
{
    __shared__ float Ws[64 * 17];
    __shared__ float Xs[16 * 132];
    __shared__ float Ob[64 * 132];

    const int ntile = blockIdx.x, otile = blockIdx.y, b = blockIdx.z;
    const int sel = otile >> 1;
    const int obase = (otile & 1) * 64;
    const float* Wm; const float* bias;
    if (sel == 0)      { Wm = tw; bias = tb; }
    else if (sel == 1) { Wm = pw; bias = pb; }
    else               { Wm = gw; bias = gb; }

    const int tid = threadIdx.x;
    const int tx = tid & 15, ty = tid >> 4;
    const int nbase = ntile * 128;

    float acc[4][8];
    gemm_core<CC>(Wm + obase * CC, x + (size_t)b * CC * NN, nbase, acc, Ws, Xs);

#pragma unroll
    for (int i = 0; i < 4; ++i) {
        const float bv = bias[obase + ty * 4 + i];
#pragma unroll
        for (int j = 0; j < 8; ++j) acc[i][j] += bv;
    }

    if (sel == 0) {
#pragma unroll
        for (int i = 0; i < 4; ++i) {
            const size_t base = ((size_t)b * CI + obase + ty * 4 + i) * NN + nbase + tx * 8;
            *(float4*)&theta[base]     = make_float4(acc[i][0], acc[i][1], acc[i][2], acc[i][3]);
            *(float4*)&theta[base + 4] = make_float4(acc[i][4], acc[i][5], acc[i][6], acc[i][7]);
        }
    } else {
#pragma unroll
        for (int i = 0; i < 4; ++i) {
            *(float4*)&Ob[(ty * 4 + i) * 132 + tx * 8]     = make_float4(acc[i][0], acc[i][1], acc[i][2], acc[i][3]);
            *(float4*)&Ob[(ty * 4 + i) * 132 + tx * 8 + 4] = make_float4(acc[i][4], acc[i][5], acc[i][6], acc[i][7]);
        }
        __syncthreads();
        float* dst = (sel == 1) ? phip : gp;
        const int t = nbase >> 10;
        const int h0 = (nbase >> 5) & 31;             // multiple of 4
        const int mbase = t * 256 + (h0 >> 1) * 16;
        for (int idx = tid; idx < 2048; idx += 256) {
            const int o = idx >> 5, ml = idx & 31;
            const int hh = ml >> 4, wp = ml & 15;
            const float* r0 = &Ob[o * 132 + hh * 64 + wp * 2];
            const float v = fmaxf(fmaxf(r0[0], r0[1]), fmaxf(r0[32], r0[33]));
            dst[((size_t)b * CI + obase + o) * MM + mbase + hh * 16 + wp] = v;
        }
    }
}

// ---------------------------------------------------------------------------
// K2: flash attention.  grid: (128 qtiles, 2 b), 256 threads.
// Q-tile 64, K-tile 32, d=128, online softmax; y stored [b][ci][n]
// ---------------------------------------------------------------------------
__global__ __launch_bounds__(256) void k_attn(
    const float* __restrict__ theta, const float* __restrict__ phip,
    const float* __restrict__ gp, float* __restrict__ y)
{
    __shared__ float th_s[128 * 64];   // theta [ci][q]
    __shared__ float un[4224];         // union: phi [128][32]  |  g [32][132]
    __shared__ float S_lds[64 * 36];   // scores/probs [q][k], pad 36
    __shared__ float m_sm[64], l_sm[64], sc_sm[64];

    const int qt = blockIdx.x, b = blockIdx.y;
    const int qbase = qt * 64;
    const int tid = threadIdx.x;
    const float* TH = theta + (size_t)b * CI * NN;
    const float* PH = phip + (size_t)b * CI * MM;
    const float* GG = gp   + (size_t)b * CI * MM;

    for (int idx = tid; idx < 128 * 16; idx += 256) {
        const int ci = idx >> 4, q4 = (idx & 15) << 2;
        *(float4*)&th_s[ci * 64 + q4] = *(const float4*)&TH[(size_t)ci * NN + qbase + q4];
    }
    if (tid < 64) { m_sm[tid] = -1e30f; l_sm[tid] = 0.f; }

    const int tq = tid & 15, tk = tid >> 4;
    const int q4 = tq * 4, k2 = tk * 2, c8 = tk * 8;

    float yacc[4][8];
#pragma unroll
    for (int i = 0; i < 4; ++i)
#pragma unroll
        for (int j = 0; j < 8; ++j) yacc[i][j] = 0.f;

    for (int kt = 0; kt < 64; ++kt) {
        const int kbase = kt * 32;
        __syncthreads();   // A: prev PV done (and initial staging done)
        // stage phi [ci][32]
        for (int idx = tid; idx < 128 * 8; idx += 256) {
            const int ci = idx >> 3, kk4 = (idx & 7) << 2;
            *(float4*)&un[ci * 32 + kk4] = *(const float4*)&PH[(size_t)ci * MM + kbase + kk4];
        }
        __syncthreads();   // B
        // S = theta^T phi  (4q x 2k per thread)
        float s[4][2];
#pragma unroll
        for (int i = 0; i < 4; ++i) { s[i][0] = 0.f; s[i][1] = 0.f; }
#pragma unroll 4
        for (int ci = 0; ci < 128; ++ci) {
            const float4 tv = *(const float4*)&th_s[ci * 64 + q4];
            const float2 pv = *(const float2*)&un[ci * 32 + k2];
            s[0][0] = fmaf(tv.x, pv.x, s[0][0]); s[0][1] = fmaf(tv.x, pv.y, s[0][1]);
            s[1][0] = fmaf(tv.y, pv.x, s[1][0]); s[1][1] = fmaf(tv.y, pv.y, s[1][1]);
            s[2][0] = fmaf(tv.z, pv.x, s[2][0]); s[2][1] = fmaf(tv.z, pv.y, s[2][1]);
            s[3][0] = fmaf(tv.w, pv.x, s[3][0]); s[3][1] = fmaf(tv.w, pv.y, s[3][1]);
        }
#pragma unroll
        for (int qi = 0; qi < 4; ++qi)
            *(float2*)&S_lds[(q4 + qi) * 36 + k2] = make_float2(s[qi][0], s[qi][1]);
        __syncthreads();   // C
        // online softmax: 4 threads per row, 8 keys each
        {
            const int row = tid >> 2, part = tid & 3;
            const float mprev = m_sm[row];
            float4 a = *(float4*)&S_lds[row * 36 + part * 8];
            float4 c = *(float4*)&S_lds[row * 36 + part * 8 + 4];
            float mx = fmaxf(fmaxf(fmaxf(a.x, a.y), fmaxf(a.z, a.w)),
                             fmaxf(fmaxf(c.x, c.y), fmaxf(c.z, c.w)));
            mx = fmaxf(mx, __shfl_xor(mx, 1));
            mx = fmaxf(mx, __shfl_xor(mx, 2));
            const float mnew = fmaxf(mprev, mx);
            const float scale = __expf(mprev - mnew);
            a.x = __expf(a.x - mnew); a.y = __expf(a.y - mnew);
            a.z = __expf(a.z - mnew); a.w = __expf(a.w - mnew);
            c.x = __expf(c.x - mnew); c.y = __expf(c.y - mnew);
            c.z = __expf(c.z - mnew); c.w = __expf(c.w - mnew);
            float sum = a.x + a.y + a.z + a.w + c.x + c.y + c.z + c.w;
            sum += __shfl_xor(sum, 1);
            sum += __shfl_xor(sum, 2);
            *(float4*)&S_lds[row * 36 + part * 8]     = a;
            *(float4*)&S_lds[row * 36 + part * 8 + 4] = c;
            if (part == 0) {
                m_sm[row] = mnew;
                l_sm[row] = l_sm[row] * scale + sum;
                sc_sm[row] = scale;
            }
        }
        // stage g (transposed -> [k][ci], pad 132); phi reads finished at C
        for (int idx = tid; idx < 4096; idx += 256) {
            const int ci = idx >> 5, kk = idx & 31;
            un[kk * 132 + ci] = GG[(size_t)ci * MM + kbase + kk];
        }
        __syncthreads();   // D
        // rescale + PV (4q x 8ci per thread)
        float sc[4];
#pragma unroll
        for (int qi = 0; qi < 4; ++qi) sc[qi] = sc_sm[q4 + qi];
#pragma unroll
        for (int qi = 0; qi < 4; ++qi)
#pragma unroll
            for (int j = 0; j < 8; ++j) yacc[qi][j] *= sc[qi];

        for (int k0 = 0; k0 < 32; k0 += 4) {
            float pr[4][4];
#pragma unroll
            for (int qi = 0; qi < 4; ++qi)
                *(float4*)&pr[qi][0] = *(const float4*)&S_lds[(q4 + qi) * 36 + k0];
#pragma unroll
            for (int kk = 0; kk < 4; ++kk) {
                const float4 ga = *(const float4*)&un[(k0 + kk) * 132 + c8];
                const float4 gb = *(const float4*)&un[(k0 + kk) * 132 + c8 + 4];
#pragma unroll
                for (int qi = 0; qi < 4; ++qi) {
                    const float p_ = pr[qi][kk];
                    yacc[qi][0] = fmaf(p_, ga.x, yacc[qi][0]);
                    yacc[qi][1] = fmaf(p_, ga.y, yacc[qi][1]);
                    yacc[qi][2] = fmaf(p_, ga.z, yacc[qi][2]);
                    yacc[qi][3] = fmaf(p_, ga.w, yacc[qi][3]);
                    yacc[qi][4] = fmaf(p_, gb.x, yacc[qi][4]);
                    yacc[qi][5] = fmaf(p_, gb.y, yacc[qi][5]);
                    yacc[qi][6] = fmaf(p_, gb.z, yacc[qi][6]);
                    yacc[qi][7] = fmaf(p_, gb.w, yacc[qi][7]);
                }
            }
        }
    }
    // finalize: divide by l, store y[b][ci][n]
    float inv[4];
#pragma unroll
    for (int qi = 0; qi < 4; ++qi) inv[qi] = 1.0f / l_sm[q4 + qi];
#pragma unroll
    for (int qi = 0; qi < 4; ++qi)
#pragma unroll
        for (int j = 0; j < 8; ++j)
            y[((size_t)b * CI + c8 + j) * NN + qbase + q4 + qi] = yacc[qi][j] * inv[qi];
}

// ---------------------------------------------------------------------------
// K3: output conv (128->256) + deterministic BN partial sums
// grid: (64 ntiles, 4 otiles, 2 b)
// ---------------------------------------------------------------------------
__global__ __launch_bounds__(256) void k_outconv(
    const float* __restrict__ yin, const float* __restrict__ ow,
    const float* __restrict__ obias, float* __restrict__ y2,
    float* __restrict__ psum, float* __restrict__ psq)
{
    __shared__ float Ws[64 * 17];
    __shared__ float Xs[16 * 132];
    const int ntile = blockIdx.x, otile = blockIdx.y, b = blockIdx.z;
    const int obase = otile * 64, nbase = ntile * 128;
    const int tid = threadIdx.x, tx = tid & 15, ty = tid >> 4;

    float acc[4][8];
    gemm_core<CI>(ow + obase * CI, yin + (size_t)b * CI * NN, nbase, acc, Ws, Xs);

#pragma unroll
    for (int i = 0; i < 4; ++i) {
        const float bv = obias[obase + ty * 4 + i];
#pragma unroll
        for (int j = 0; j < 8; ++j) acc[i][j] += bv;
    }
#pragma unroll
    for (int i = 0; i < 4; ++i) {
        const size_t base = ((size_t)b * CC + obase + ty * 4 + i) * NN + nbase + tx * 8;
        *(float4*)&y2[base]     = make_float4(acc[i][0], acc[i][1], acc[i][2], acc[i][3]);
        *(float4*)&y2[base + 4] = make_float4(acc[i][4], acc[i][5], acc[i][6], acc[i][7]);
    }
#pragma unroll
    for (int i = 0; i < 4; ++i) {
        float s = 0.f, q = 0.f;
#pragma unroll
        for (int j = 0; j < 8; ++j) { s += acc[i][j]; q += acc[i][j] * acc[i][j]; }
#pragma unroll
        for (int d = 1; d < 16; d <<= 1) { s += __shfl_xor(s, d); q += __shfl_xor(q, d); }
        if (tx == 0) {
            const int co = obase + ty * 4 + i;
            psum[co * 128 + b * 64 + ntile] = s;
            psq [co * 128 + b * 64 + ntile] = q;
        }
    }
}

// K4: reduce partials -> mean, inv_std
__global__ void k_red(const float* __restrict__ psum, const float* __restrict__ psq,
                      float* __restrict__ stats)
{
    const int co = threadIdx.x;
    float s = 0.f, q = 0.f;
    for (int i = 0; i < 128; ++i) { s += psum[co * 128 + i]; q += psq[co * 128 + i]; }
    const float mean = s * (1.f / 16384.f);
    const float var = q * (1.f / 16384.f) - mean * mean;
    stats[co] = mean;
    stats[256 + co] = rsqrtf(var + 1e-5f);
}

// K5: out = x + bn(y2) ; y2 lives in d_out, in-place
__global__ __launch_bounds__(256) void k_bn(
    const float* __restrict__ x, const float* __restrict__ bw,
    const float* __restrict__ bb, const float* __restrict__ stats,
    float* __restrict__ out)
{
    const int i4 = blockIdx.x * 256 + threadIdx.x;   // 1048576 float4s exactly
    const int c = (i4 >> 11) & 255;
    const float a = stats[256 + c] * bw[c];
    const float bias2 = bb[c] - stats[c] * a;
    const float4 v = ((const float4*)out)[i4];
    const float4 xv = ((const float4*)x)[i4];
    float4 r;
    r.x = xv.x + v.x * a + bias2;
    r.y = xv.y + v.y * a + bias2;
    r.z = xv.z + v.z * a + bias2;
    r.w = xv.w + v.w * a + bias2;
    ((float4*)out)[i4] = r;
}

extern "C" void kernel_launch(void* const* d_in, const int* in_sizes, int n_in,
                              void* d_out, int out_size, void* d_ws, size_t ws_size,
                              hipStream_t stream) {
    const float* x       = (const float*)d_in[0];
    const float* g_w     = (const float*)d_in[1];
    const float* g_b     = (const float*)d_in[2];
    const float* theta_w = (const float*)d_in[3];
    const float* theta_b = (const float*)d_in[4];
    const float* phi_w   = (const float*)d_in[5];
    const float* phi_b   = (const float*)d_in[6];
    const float* out_w   = (const float*)d_in[7];
    const float* out_b   = (const float*)d_in[8];
    const float* bn_w    = (const float*)d_in[9];
    const float* bn_b    = (const float*)d_in[10];

    float* ws    = (float*)d_ws;
    float* theta = ws + OFF_THETA;
    float* phip  = ws + OFF_PHIP;
    float* gp    = ws + OFF_GP;
    float* yws   = ws + OFF_Y;
    float* psum  = ws + OFF_PSUM;
    float* psq   = ws + OFF_PSQ;
    float* stats = ws + OFF_STAT;
    float* out   = (float*)d_out;

    k_qkv<<<dim3(64, 6, 2), 256, 0, stream>>>(x, theta_w, theta_b, phi_w, phi_b,
                                              g_w, g_b, theta, phip, gp);
    k_attn<<<dim3(128, 2), 256, 0, stream>>>(theta, phip, gp, yws);
    k_outconv<<<dim3(64, 4, 2), 256, 0, stream>>>(yws, out_w, out_b, out, psum, psq);
    k_red<<<1, 256, 0, stream>>>(psum, psq, stats);
    k_bn<<<4096, 256, 0, stream>>>(x, bn_w, bn_b, stats, out);
}

// Round 2
// 152.054 us; speedup vs baseline: 4.1507x; 4.1507x over previous
//
#include <hip/hip_runtime.h>
#include <math.h>

#define CC 256
#define CI 128
#define NN 8192
#define MM 2048
#define NSPLIT 4
#define KSPAN 512
#define KT 32
#define NTILES 16

typedef __attribute__((ext_vector_type(8))) short bf16x8;
typedef __attribute__((ext_vector_type(4))) float f32x4;

// ws byte offsets
#define OFF_THETA16 0u
#define OFF_PHI16   4194304u
#define OFF_G16     5242880u
#define OFF_Y16     6291456u
#define OFF_M       10485760u
#define OFF_L       10747904u
#define OFF_PSUM    11010048u
#define OFF_PSQ     11141120u
#define OFF_STAT    11272192u

static __device__ __forceinline__ unsigned short f2bfbits(float x) {
    unsigned u = __builtin_bit_cast(unsigned, x);
    u = u + 0x7fffu + ((u >> 16) & 1u);
    return (unsigned short)(u >> 16);
}
static __device__ __forceinline__ float bf2f(unsigned short h) {
    return __builtin_bit_cast(float, ((unsigned)h) << 16);
}
static __device__ __forceinline__ void gll16(const void* g, void* l) {
    __builtin_amdgcn_global_load_lds(
        (const __attribute__((address_space(1))) unsigned int*)g,
        (__attribute__((address_space(3))) unsigned int*)l, 16, 0, 0);
}

// ---------------------------------------------------------------------------
// fp32 GEMM core (K1): Out[64 o][128 n] = W[64][CIN] * X[CIN][NN]-tile
// ---------------------------------------------------------------------------
template<int CIN>
__device__ __forceinline__ void gemm_core(const float* __restrict__ Wm,
                                          const float* __restrict__ X,
                                          int nbase, float (&acc)[4][8],
                                          float* __restrict__ Ws,
                                          float* __restrict__ Xs)
{
    const int tid = threadIdx.x;
    const int tx = tid & 15, ty = tid >> 4;
#pragma unroll
    for (int i = 0; i < 4; ++i)
#pragma unroll
        for (int j = 0; j < 8; ++j) acc[i][j] = 0.f;

    for (int c0 = 0; c0 < CIN; c0 += 16) {
        __syncthreads();
        for (int idx = tid; idx < 1024; idx += 256) {
            const int o = idx >> 4, kk = idx & 15;
            Ws[o * 17 + kk] = Wm[o * CIN + c0 + kk];
        }
        for (int idx = tid; idx < 512; idx += 256) {
            const int kk = idx >> 5, n4 = (idx & 31) << 2;
            *(float4*)&Xs[kk * 132 + n4] =
                *(const float4*)&X[(size_t)(c0 + kk) * NN + nbase + n4];
        }
        __syncthreads();
#pragma unroll
        for (int kk = 0; kk < 16; ++kk) {
            float xv[8], wv[4];
            *(float4*)&xv[0] = *(const float4*)&Xs[kk * 132 + tx * 8];
            *(float4*)&xv[4] = *(const float4*)&Xs[kk * 132 + tx * 8 + 4];
#pragma unroll
            for (int i = 0; i < 4; ++i) wv[i] = Ws[(ty * 4 + i) * 17 + kk];
#pragma unroll
            for (int i = 0; i < 4; ++i)
#pragma unroll
                for (int j = 0; j < 8; ++j)
                    acc[i][j] = fmaf(wv[i], xv[j], acc[i][j]);
        }
    }
}

// ---------------------------------------------------------------------------
// K1: theta/phi/g 1x1 convs (fp32 math), bf16 outputs:
//   thetaT [b][n][ci], phiT [b][m][ci] (pooled), g [b][ci][m] (pooled)
// grid: (64 ntiles, 6 otiles, 2 b)
// ---------------------------------------------------------------------------
__global__ __launch_bounds__(256) void k_qkv(
    const float* __restrict__ x,
    const float* __restrict__ tw, const float* __restrict__ tb,
    const float* __restrict__ pw, const float* __restrict__ pb,
    const float* __restrict__ gw, const float* __restrict__ gb,
    unsigned short* __restrict__ thetaT, unsigned short* __restrict__ phiT,
    unsigned short* __restrict__ gT)
{
    __shared__ float Ws[64 * 17];
    __shared__ float Xs[16 * 132];
    __shared__ float Ob[64 * 132];

    const int ntile = blockIdx.x, otile = blockIdx.y, b = blockIdx.z;
    const int sel = otile >> 1;
    const int obase = (otile & 1) * 64;
    const float* Wm; const float* bias;
    if (sel == 0)      { Wm = tw; bias = tb; }
    else if (sel == 1) { Wm = pw; bias = pb; }
    else               { Wm = gw; bias = gb; }

    const int tid = threadIdx.x;
    const int tx = tid & 15, ty = tid >> 4;
    const int nbase = ntile * 128;

    float acc[4][8];
    gemm_core<CC>(Wm + obase * CC, x + (size_t)b * CC * NN, nbase, acc, Ws, Xs);

#pragma unroll
    for (int i = 0; i < 4; ++i) {
        const float bv = bias[obase + ty * 4 + i];
#pragma unroll
        for (int j = 0; j < 8; ++j) acc[i][j] += bv;
    }

    // park tile in LDS [64 o][132 n]
#pragma unroll
    for (int i = 0; i < 4; ++i) {
        *(float4*)&Ob[(ty * 4 + i) * 132 + tx * 8]     = make_float4(acc[i][0], acc[i][1], acc[i][2], acc[i][3]);
        *(float4*)&Ob[(ty * 4 + i) * 132 + tx * 8 + 4] = make_float4(acc[i][4], acc[i][5], acc[i][6], acc[i][7]);
    }
    __syncthreads();

    if (sel == 0) {
        unsigned short* dst = thetaT + ((size_t)b * NN + nbase) * CI + obase;
        for (int idx = tid; idx < 8192; idx += 256) {
            const int n = idx >> 6, o = idx & 63;
            dst[(size_t)n * CI + o] = f2bfbits(Ob[o * 132 + n]);
        }
    } else {
        const int t = nbase >> 10;
        const int h0 = (nbase >> 5) & 31;
        const int mbase = t * 256 + (h0 >> 1) * 16;
        if (sel == 1) {
            for (int idx = tid; idx < 2048; idx += 256) {
                const int ml = idx >> 6, o = idx & 63;
                const int hh = ml >> 4, wp = ml & 15;
                const float* r0 = &Ob[o * 132 + hh * 64 + wp * 2];
                const float v = fmaxf(fmaxf(r0[0], r0[1]), fmaxf(r0[32], r0[33]));
                phiT[((size_t)b * MM + mbase + hh * 16 + wp) * CI + obase + o] = f2bfbits(v);
            }
        } else {
            for (int idx = tid; idx < 2048; idx += 256) {
                const int o = idx >> 5, ml = idx & 31;
                const int hh = ml >> 4, wp = ml & 15;
                const float* r0 = &Ob[o * 132 + hh * 64 + wp * 2];
                const float v = fmaxf(fmaxf(r0[0], r0[1]), fmaxf(r0[32], r0[33]));
                gT[((size_t)b * CI + obase + o) * MM + mbase + hh * 16 + wp] = f2bfbits(v);
            }
        }
    }
}

// ---------------------------------------------------------------------------
// K2: flash attention, bf16 MFMA. grid (64 qblk, NSPLIT, 2 b), 256 thr (4 waves)
// Each wave: 32 queries (2 x 16). KT=32 keys/tile, double-buffered LDS.
// Computes S^T = phi*theta^T (swapped) -> lane-local softmax -> P->bf16 via
// per-wave LDS repack -> y^T += g^T * P^T. Writes unnormalized partials + m,l.
// ---------------------------------------------------------------------------
__global__ __launch_bounds__(256, 2) void k_attn(
    const unsigned short* __restrict__ thetaT,
    const unsigned short* __restrict__ phiT,
    const unsigned short* __restrict__ gT,
    unsigned short* __restrict__ yp,
    float* __restrict__ mbuf, float* __restrict__ lbuf)
{
    __shared__ __align__(16) char smem[40960];  // 2x(8K phi + 8K g) + 8K P
    const int tid  = threadIdx.x;
    const int wave = tid >> 6;
    const int lane = tid & 63;
    const int lq = lane & 15, G = lane >> 4;
    const int qblk = blockIdx.x, s = blockIdx.y, b = blockIdx.z;
    const int qbase = qblk * 128 + wave * 32;
    const int koff0 = s * KSPAN;

    // theta fragments in registers for the whole kernel (B-operand of S^T)
    bf16x8 tf[2][4];
#pragma unroll
    for (int qt = 0; qt < 2; ++qt) {
        const size_t row = (size_t)b * NN + qbase + qt * 16 + lq;
#pragma unroll
        for (int D = 0; D < 4; ++D)
            tf[qt][D] = *(const bf16x8*)(thetaT + row * CI + D * 32 + G * 8);
    }

    // staging invariants (pre-swizzled global source, linear LDS dest)
    const char* phiSrc = (const char*)(phiT + (size_t)b * MM * CI);
    const char* gSrc   = (const char*)(gT   + (size_t)b * CI * MM);
    int pk[2], pco[2], gci[2];
#pragma unroll
    for (int i = 0; i < 2; ++i) {
        const int kr = i * 4 + (lane >> 4);
        pk[i]  = wave * 8 + kr;
        pco[i] = ((lane & 15) ^ (kr & 7)) << 4;
        gci[i] = wave * 32 + i * 16 + (lane >> 2);
    }
    const int gco = ((lane & 3) ^ ((lane >> 2) & 3)) << 4;

    auto STAGE = [&](int buf, int koff) {
        char* pl = smem + buf * 16384 + wave * 2048;
        char* gl = smem + buf * 16384 + 8192 + wave * 2048;
#pragma unroll
        for (int i = 0; i < 2; ++i) {
            gll16(phiSrc + (size_t)(koff + pk[i]) * 256 + pco[i], pl + i * 1024);
            gll16(gSrc + (size_t)gci[i] * 4096 + (size_t)koff * 2 + gco, gl + i * 1024);
        }
    };

    f32x4 yacc[2][8];
#pragma unroll
    for (int qt = 0; qt < 2; ++qt)
#pragma unroll
        for (int c = 0; c < 8; ++c) yacc[qt][c] = (f32x4){0.f, 0.f, 0.f, 0.f};
    float mreg[2] = {-1e30f, -1e30f};
    float lreg[2] = {0.f, 0.f};

    STAGE(0, koff0);
    __syncthreads();

    char* pP = smem + 32768 + wave * 2048;
    const int swq = (lq & 3) << 4;
    const int swk = (lq & 7) << 4;

    for (int t = 0; t < NTILES; ++t) {
        const int cur = t & 1;
        if (t < NTILES - 1) STAGE(cur ^ 1, koff0 + (t + 1) * KT);
        const char* pbuf = smem + cur * 16384;
        const char* gbuf = smem + cur * 16384 + 8192;

        // S^T = phi * theta^T   (2 q-tiles x 2 k-subtiles)
        f32x4 sacc[2][2];
#pragma unroll
        for (int qt = 0; qt < 2; ++qt)
#pragma unroll
            for (int ks = 0; ks < 2; ++ks) sacc[qt][ks] = (f32x4){0.f, 0.f, 0.f, 0.f};
#pragma unroll
        for (int D = 0; D < 4; ++D) {
            const int co = (((D * 4 + G) << 4) ^ swk);
            const bf16x8 a0 = *(const bf16x8*)(pbuf + lq * 256 + co);
            const bf16x8 a1 = *(const bf16x8*)(pbuf + (16 + lq) * 256 + co);
            sacc[0][0] = __builtin_amdgcn_mfma_f32_16x16x32_bf16(a0, tf[0][D], sacc[0][0], 0, 0, 0);
            sacc[1][0] = __builtin_amdgcn_mfma_f32_16x16x32_bf16(a0, tf[1][D], sacc[1][0], 0, 0, 0);
            sacc[0][1] = __builtin_amdgcn_mfma_f32_16x16x32_bf16(a1, tf[0][D], sacc[0][1], 0, 0, 0);
            sacc[1][1] = __builtin_amdgcn_mfma_f32_16x16x32_bf16(a1, tf[1][D], sacc[1][1], 0, 0, 0);
        }

        // online softmax (per lane: 8 keys of its q row), pack P -> LDS
#pragma unroll
        for (int qt = 0; qt < 2; ++qt) {
            float p[8];
            float mx = -1e30f;
#pragma unroll
            for (int ks = 0; ks < 2; ++ks)
#pragma unroll
                for (int r = 0; r < 4; ++r) mx = fmaxf(mx, sacc[qt][ks][r]);
            mx = fmaxf(mx, __shfl_xor(mx, 16));
            mx = fmaxf(mx, __shfl_xor(mx, 32));
            const float mnew = fmaxf(mreg[qt], mx);
            const float scale = __expf(mreg[qt] - mnew);
            float sum = 0.f;
#pragma unroll
            for (int ks = 0; ks < 2; ++ks)
#pragma unroll
                for (int r = 0; r < 4; ++r) {
                    const float e = __expf(sacc[qt][ks][r] - mnew);
                    p[ks * 4 + r] = e;
                    sum += e;
                }
            sum += __shfl_xor(sum, 16);
            sum += __shfl_xor(sum, 32);
            mreg[qt] = mnew;
            lreg[qt] = lreg[qt] * scale + sum;
#pragma unroll
            for (int c = 0; c < 8; ++c) yacc[qt][c] *= scale;
#pragma unroll
            for (int ks = 0; ks < 2; ++ks)
#pragma unroll
                for (int r2 = 0; r2 < 2; ++r2) {
                    const unsigned w = (unsigned)f2bfbits(p[ks * 4 + r2 * 2]) |
                                       ((unsigned)f2bfbits(p[ks * 4 + r2 * 2 + 1]) << 16);
                    const int byt = (ks * 32 + G * 8 + r2 * 4) ^ swq;
                    *(unsigned*)(pP + qt * 1024 + lq * 64 + byt) = w;
                }
        }

        // PV: y^T += g^T * P^T
        bf16x8 pf[2];
#pragma unroll
        for (int qt = 0; qt < 2; ++qt)
            pf[qt] = *(const bf16x8*)(pP + qt * 1024 + lq * 64 + ((G * 16) ^ swq));
#pragma unroll
        for (int c = 0; c < 8; ++c) {
            const int row = c * 16 + lq;
            const bf16x8 gf = *(const bf16x8*)(gbuf + row * 64 + ((G * 16) ^ swq));
            yacc[0][c] = __builtin_amdgcn_mfma_f32_16x16x32_bf16(gf, pf[0], yacc[0][c], 0, 0, 0);
            yacc[1][c] = __builtin_amdgcn_mfma_f32_16x16x32_bf16(gf, pf[1], yacc[1][c], 0, 0, 0);
        }
        __syncthreads();
    }

    // epilogue: unnormalized partials (bf16) + m,l
    const int sb = b * NSPLIT + s;
    if (lane < 16) {
#pragma unroll
        for (int qt = 0; qt < 2; ++qt) {
            const int n = qbase + qt * 16 + lq;
            mbuf[(size_t)sb * NN + n] = mreg[qt];
            lbuf[(size_t)sb * NN + n] = lreg[qt];
        }
    }
#pragma unroll
    for (int qt = 0; qt < 2; ++qt) {
        const int n = qbase + qt * 16 + lq;
#pragma unroll
        for (int c = 0; c < 8; ++c)
#pragma unroll
            for (int r = 0; r < 4; ++r) {
                const int ci = c * 16 + G * 4 + r;
                yp[((size_t)sb * CI + ci) * NN + n] = f2bfbits(yacc[qt][c][r]);
            }
    }
}

// ---------------------------------------------------------------------------
// K2b: combine K-splits -> y bf16 [b][ci][n].  grid (32, 8, 2)
// ---------------------------------------------------------------------------
__global__ __launch_bounds__(256) void k_combine(
    const unsigned short* __restrict__ yp,
    const float* __restrict__ mbuf, const float* __restrict__ lbuf,
    unsigned short* __restrict__ y16)
{
    const int n = blockIdx.x * 256 + threadIdx.x;
    const int cc = blockIdx.y, b = blockIdx.z;
    float m[NSPLIT], l[NSPLIT];
#pragma unroll
    for (int s = 0; s < NSPLIT; ++s) {
        m[s] = mbuf[(size_t)(b * NSPLIT + s) * NN + n];
        l[s] = lbuf[(size_t)(b * NSPLIT + s) * NN + n];
    }
    const float mg = fmaxf(fmaxf(m[0], m[1]), fmaxf(m[2], m[3]));
    float w[NSPLIT], denom = 0.f;
#pragma unroll
    for (int s = 0; s < NSPLIT; ++s) { w[s] = __expf(m[s] - mg); denom += l[s] * w[s]; }
    const float inv = 1.f / denom;
#pragma unroll
    for (int i = 0; i < 16; ++i) {
        const int ci = cc * 16 + i;
        float acc = 0.f;
#pragma unroll
        for (int s = 0; s < NSPLIT; ++s)
            acc += bf2f(yp[((size_t)(b * NSPLIT + s) * CI + ci) * NN + n]) * w[s];
        y16[((size_t)b * CI + ci) * NN + n] = f2bfbits(acc * inv);
    }
}

// ---------------------------------------------------------------------------
// K3: output conv (bf16 in, 128->256) + deterministic BN partial sums
// grid: (64 ntiles, 4 otiles, 2 b)
// ---------------------------------------------------------------------------
__global__ __launch_bounds__(256) void k_outconv(
    const unsigned short* __restrict__ yin, const float* __restrict__ ow,
    const float* __restrict__ obias, float* __restrict__ y2,
    float* __restrict__ psum, float* __restrict__ psq)
{
    __shared__ float Ws[64 * 17];
    __shared__ float Xs[16 * 132];
    const int ntile = blockIdx.x, otile = blockIdx.y, b = blockIdx.z;
    const int obase = otile * 64, nbase = ntile * 128;
    const int tid = threadIdx.x, tx = tid & 15, ty = tid >> 4;
    const float* Wm = ow + obase * CI;
    const unsigned short* Xb = yin + (size_t)b * CI * NN;

    float acc[4][8];
#pragma unroll
    for (int i = 0; i < 4; ++i)
#pragma unroll
        for (int j = 0; j < 8; ++j) acc[i][j] = 0.f;

    const int kks = tid >> 4, n8 = (tid & 15) * 8;
    for (int c0 = 0; c0 < CI; c0 += 16) {
        __syncthreads();
        for (int idx = tid; idx < 1024; idx += 256) {
            const int o = idx >> 4, kk = idx & 15;
            Ws[o * 17 + kk] = Wm[o * CI + c0 + kk];
        }
        {
            const uint4 u = *(const uint4*)&Xb[(size_t)(c0 + kks) * NN + nbase + n8];
            float* xr = &Xs[kks * 132 + n8];
            xr[0] = __builtin_bit_cast(float, u.x << 16);
            xr[1] = __builtin_bit_cast(float, u.x & 0xffff0000u);
            xr[2] = __builtin_bit_cast(float, u.y << 16);
            xr[3] = __builtin_bit_cast(float, u.y & 0xffff0000u);
            xr[4] = __builtin_bit_cast(float, u.z << 16);
            xr[5] = __builtin_bit_cast(float, u.z & 0xffff0000u);
            xr[6] = __builtin_bit_cast(float, u.w << 16);
            xr[7] = __builtin_bit_cast(float, u.w & 0xffff0000u);
        }
        __syncthreads();
#pragma unroll
        for (int kk = 0; kk < 16; ++kk) {
            float xv[8], wv[4];
            *(float4*)&xv[0] = *(const float4*)&Xs[kk * 132 + tx * 8];
            *(float4*)&xv[4] = *(const float4*)&Xs[kk * 132 + tx * 8 + 4];
#pragma unroll
            for (int i = 0; i < 4; ++i) wv[i] = Ws[(ty * 4 + i) * 17 + kk];
#pragma unroll
            for (int i = 0; i < 4; ++i)
#pragma unroll
                for (int j = 0; j < 8; ++j)
                    acc[i][j] = fmaf(wv[i], xv[j], acc[i][j]);
        }
    }

#pragma unroll
    for (int i = 0; i < 4; ++i) {
        const float bv = obias[obase + ty * 4 + i];
#pragma unroll
        for (int j = 0; j < 8; ++j) acc[i][j] += bv;
    }
#pragma unroll
    for (int i = 0; i < 4; ++i) {
        const size_t base = ((size_t)b * CC + obase + ty * 4 + i) * NN + nbase + tx * 8;
        *(float4*)&y2[base]     = make_float4(acc[i][0], acc[i][1], acc[i][2], acc[i][3]);
        *(float4*)&y2[base + 4] = make_float4(acc[i][4], acc[i][5], acc[i][6], acc[i][7]);
    }
#pragma unroll
    for (int i = 0; i < 4; ++i) {
        float sv = 0.f, q = 0.f;
#pragma unroll
        for (int j = 0; j < 8; ++j) { sv += acc[i][j]; q += acc[i][j] * acc[i][j]; }
#pragma unroll
        for (int d = 1; d < 16; d <<= 1) { sv += __shfl_xor(sv, d); q += __shfl_xor(q, d); }
        if (tx == 0) {
            const int co = obase + ty * 4 + i;
            psum[co * 128 + b * 64 + ntile] = sv;
            psq [co * 128 + b * 64 + ntile] = q;
        }
    }
}

// K4: reduce partials -> mean, inv_std
__global__ void k_red(const float* __restrict__ psum, const float* __restrict__ psq,
                      float* __restrict__ stats)
{
    const int co = threadIdx.x;
    float s = 0.f, q = 0.f;
    for (int i = 0; i < 128; ++i) { s += psum[co * 128 + i]; q += psq[co * 128 + i]; }
    const float mean = s * (1.f / 16384.f);
    const float var = q * (1.f / 16384.f) - mean * mean;
    stats[co] = mean;
    stats[256 + co] = rsqrtf(var + 1e-5f);
}

// K5: out = x + bn(y2) ; y2 lives in d_out, in-place
__global__ __launch_bounds__(256) void k_bn(
    const float* __restrict__ x, const float* __restrict__ bw,
    const float* __restrict__ bb, const float* __restrict__ stats,
    float* __restrict__ out)
{
    const int i4 = blockIdx.x * 256 + threadIdx.x;
    const int c = (i4 >> 11) & 255;
    const float a = stats[256 + c] * bw[c];
    const float bias2 = bb[c] - stats[c] * a;
    const float4 v = ((const float4*)out)[i4];
    const float4 xv = ((const float4*)x)[i4];
    float4 r;
    r.x = xv.x + v.x * a + bias2;
    r.y = xv.y + v.y * a + bias2;
    r.z = xv.z + v.z * a + bias2;
    r.w = xv.w + v.w * a + bias2;
    ((float4*)out)[i4] = r;
}

extern "C" void kernel_launch(void* const* d_in, const int* in_sizes, int n_in,
                              void* d_out, int out_size, void* d_ws, size_t ws_size,
                              hipStream_t stream) {
    const float* x       = (const float*)d_in[0];
    const float* g_w     = (const float*)d_in[1];
    const float* g_b     = (const float*)d_in[2];
    const float* theta_w = (const float*)d_in[3];
    const float* theta_b = (const float*)d_in[4];
    const float* phi_w   = (const float*)d_in[5];
    const float* phi_b   = (const float*)d_in[6];
    const float* out_w   = (const float*)d_in[7];
    const float* out_b   = (const float*)d_in[8];
    const float* bn_w    = (const float*)d_in[9];
    const float* bn_b    = (const float*)d_in[10];

    char* ws = (char*)d_ws;
    unsigned short* theta16 = (unsigned short*)(ws + OFF_THETA16);
    unsigned short* phi16   = (unsigned short*)(ws + OFF_PHI16);
    unsigned short* g16     = (unsigned short*)(ws + OFF_G16);
    unsigned short* y16     = (unsigned short*)(ws + OFF_Y16);
    float* mbuf  = (float*)(ws + OFF_M);
    float* lbuf  = (float*)(ws + OFF_L);
    float* psum  = (float*)(ws + OFF_PSUM);
    float* psq   = (float*)(ws + OFF_PSQ);
    float* stats = (float*)(ws + OFF_STAT);
    float* out   = (float*)d_out;
    unsigned short* yp = (unsigned short*)d_out;   // split partials park in d_out (dead until K3)

    k_qkv<<<dim3(64, 6, 2), 256, 0, stream>>>(x, theta_w, theta_b, phi_w, phi_b,
                                              g_w, g_b, theta16, phi16, g16);
    k_attn<<<dim3(64, NSPLIT, 2), 256, 0, stream>>>(theta16, phi16, g16, yp, mbuf, lbuf);
    k_combine<<<dim3(32, 8, 2), 256, 0, stream>>>(yp, mbuf, lbuf, y16);
    k_outconv<<<dim3(64, 4, 2), 256, 0, stream>>>(y16, out_w, out_b, out, psum, psq);
    k_red<<<1, 256, 0, stream>>>(psum, psq, stats);
    k_bn<<<4096, 256, 0, stream>>>(x, bn_w, bn_b, stats, out);
}

// Round 3
// 119.162 us; speedup vs baseline: 5.2965x; 1.2760x over previous
//
#include <hip/hip_runtime.h>
#include <math.h>

#define CC 256
#define CI 128
#define NN 8192
#define MM 2048
#define NSPLIT 4
#define KSPAN 512
#define KT 32
#define NTILES 16

typedef __attribute__((ext_vector_type(8))) short bf16x8;
typedef __attribute__((ext_vector_type(4))) float f32x4;

// ws byte offsets
#define OFF_XT      0u
#define OFF_WQH     8388608u
#define OFF_WQL     8585216u
#define OFF_WOH     8781824u
#define OFF_WOL     8847360u
#define OFF_THETA16 8912896u
#define OFF_PHI16   13107200u
#define OFF_G16     14155776u
#define OFF_Y16     15204352u
#define OFF_M       19398656u
#define OFF_L       19660800u
#define OFF_PSUM    19922944u
#define OFF_PSQ     20054016u
#define OFF_STAT    20185088u

static __device__ __forceinline__ unsigned short f2bfbits(float x) {
    unsigned u = __builtin_bit_cast(unsigned, x);
    u = u + 0x7fffu + ((u >> 16) & 1u);
    return (unsigned short)(u >> 16);
}
static __device__ __forceinline__ float bf2f(unsigned short h) {
    return __builtin_bit_cast(float, ((unsigned)h) << 16);
}
static __device__ __forceinline__ void gll16(const void* g, void* l) {
    __builtin_amdgcn_global_load_lds(
        (const __attribute__((address_space(1))) unsigned int*)g,
        (__attribute__((address_space(3))) unsigned int*)l, 16, 0, 0);
}

// ---------------------------------------------------------------------------
// K0a: weights -> bf16 hi/lo.  Wq = [theta;phi;g] stacked [384][256]; Wo [256][128]
// grid (512), 256 thr
// ---------------------------------------------------------------------------
__global__ __launch_bounds__(256) void k_prep(
    const float* __restrict__ tw, const float* __restrict__ pw,
    const float* __restrict__ gw, const float* __restrict__ ow,
    unsigned short* __restrict__ wqh, unsigned short* __restrict__ wql,
    unsigned short* __restrict__ woh, unsigned short* __restrict__ wol)
{
    const int i = blockIdx.x * 256 + threadIdx.x;
    if (i < 98304) {
        const float v = (i < 32768) ? tw[i] : (i < 65536) ? pw[i - 32768] : gw[i - 65536];
        const unsigned short h = f2bfbits(v);
        wqh[i] = h;
        wql[i] = f2bfbits(v - bf2f(h));
    } else {
        const int j = i - 98304;
        const float v = ow[j];
        const unsigned short h = f2bfbits(v);
        woh[j] = h;
        wol[j] = f2bfbits(v - bf2f(h));
    }
}

// ---------------------------------------------------------------------------
// K0b: x [b][256 c][8192 n] fp32 -> xT [b][n][256 c] bf16 (LDS transpose)
// grid (128 nb, 4 cb, 2 b)
// ---------------------------------------------------------------------------
__global__ __launch_bounds__(256) void k_xt(const float* __restrict__ x,
                                            unsigned short* __restrict__ xT)
{
    __shared__ float Xl[64 * 68];
    const int nb = blockIdx.x * 64, cb = blockIdx.y * 64, b = blockIdx.z;
    const int t = threadIdx.x;
    const float* xb = x + ((size_t)b * CC + cb) * NN + nb;
    {
        const int cl = t >> 4, n4 = (t & 15) * 4;
#pragma unroll
        for (int i = 0; i < 4; ++i)
            *(float4*)&Xl[(cl + i * 16) * 68 + n4] =
                *(const float4*)&xb[(size_t)(cl + i * 16) * NN + n4];
    }
    __syncthreads();
    const int n = t >> 2, c0 = (t & 3) * 16;
    unsigned short v[16];
#pragma unroll
    for (int j = 0; j < 16; ++j) v[j] = f2bfbits(Xl[(c0 + j) * 68 + n]);
    unsigned short* dst = xT + ((size_t)b * NN + nb + n) * CC + cb + c0;
    *(uint4*)dst = *(uint4*)&v[0];
    *(uint4*)(dst + 8) = *(uint4*)&v[8];
}

// ---------------------------------------------------------------------------
// K1: theta/phi/g via bf16 MFMA, split-W (hi+lo) fp32-accurate.
// grid (128 nt of 64 n, 3 sel, 2 b), 256 thr = 4 waves, each wave 32 o.
// Outputs: sel0 thetaT[b][n][ci]; sel1 phiT[b][m][ci] pooled; sel2 gT[b][ci][m] pooled
// ---------------------------------------------------------------------------
__global__ __launch_bounds__(256) void k_qkvm(
    const unsigned short* __restrict__ xT,
    const unsigned short* __restrict__ wqh, const unsigned short* __restrict__ wql,
    const float* __restrict__ tb, const float* __restrict__ pb, const float* __restrict__ gb,
    unsigned short* __restrict__ thetaT, unsigned short* __restrict__ phiT,
    unsigned short* __restrict__ gT)
{
    __shared__ unsigned short park[64 * 136];   // [n][o] pad 8
    const int nt_ = blockIdx.x, sel = blockIdx.y, b = blockIdx.z;
    const int nb = nt_ * 64;
    const int tid = threadIdx.x, wave = tid >> 6, lane = tid & 63;
    const int lq = lane & 15, G = lane >> 4;
    const int obase = wave * 32;
    const int orow = sel * 128 + obase;
    const float* bias = (sel == 0) ? tb : (sel == 1) ? pb : gb;

    f32x4 acc[2][4];
#pragma unroll
    for (int ot = 0; ot < 2; ++ot)
#pragma unroll
        for (int nt = 0; nt < 4; ++nt) acc[ot][nt] = (f32x4){0.f, 0.f, 0.f, 0.f};

    const unsigned short* xrow = xT + ((size_t)b * NN + nb) * CC;
#pragma unroll
    for (int kc = 0; kc < 8; ++kc) {
        bf16x8 wh[2], wl[2], xf[4];
#pragma unroll
        for (int ot = 0; ot < 2; ++ot) {
            const size_t wr = (size_t)(orow + ot * 16 + lq) * CC + kc * 32 + G * 8;
            wh[ot] = *(const bf16x8*)(wqh + wr);
            wl[ot] = *(const bf16x8*)(wql + wr);
        }
#pragma unroll
        for (int nt = 0; nt < 4; ++nt)
            xf[nt] = *(const bf16x8*)(xrow + (size_t)(nt * 16 + lq) * CC + kc * 32 + G * 8);
#pragma unroll
        for (int ot = 0; ot < 2; ++ot)
#pragma unroll
            for (int nt = 0; nt < 4; ++nt) {
                acc[ot][nt] = __builtin_amdgcn_mfma_f32_16x16x32_bf16(wh[ot], xf[nt], acc[ot][nt], 0, 0, 0);
                acc[ot][nt] = __builtin_amdgcn_mfma_f32_16x16x32_bf16(wl[ot], xf[nt], acc[ot][nt], 0, 0, 0);
            }
    }
    // bias (fp32)
#pragma unroll
    for (int ot = 0; ot < 2; ++ot) {
        const float4 bv = *(const float4*)&bias[obase + ot * 16 + G * 4];
#pragma unroll
        for (int nt = 0; nt < 4; ++nt) {
            acc[ot][nt][0] += bv.x; acc[ot][nt][1] += bv.y;
            acc[ot][nt][2] += bv.z; acc[ot][nt][3] += bv.w;
        }
    }

    if (sel == 0) {
        // direct store thetaT [n][ci], 8B per (ot,nt)
#pragma unroll
        for (int ot = 0; ot < 2; ++ot)
#pragma unroll
            for (int nt = 0; nt < 4; ++nt) {
                unsigned short pk[4];
#pragma unroll
                for (int r = 0; r < 4; ++r) pk[r] = f2bfbits(acc[ot][nt][r]);
                const int n = nb + nt * 16 + lq;
                const int ci = obase + ot * 16 + G * 4;
                *(uint2*)&thetaT[((size_t)b * NN + n) * CI + ci] = *(uint2*)pk;
            }
    } else {
        // park [n][o] bf16, then 2x2 max-pool
#pragma unroll
        for (int ot = 0; ot < 2; ++ot)
#pragma unroll
            for (int nt = 0; nt < 4; ++nt) {
                unsigned short pk[4];
#pragma unroll
                for (int r = 0; r < 4; ++r) pk[r] = f2bfbits(acc[ot][nt][r]);
                const int n = nt * 16 + lq;
                const int o = obase + ot * 16 + G * 4;
                *(uint2*)&park[n * 136 + o] = *(uint2*)pk;
            }
        __syncthreads();
        const int tfrm = nb >> 10, h0 = (nb >> 5) & 31;
        const int mb = tfrm * 256 + (h0 >> 1) * 16;
        if (sel == 1) {
            for (int idx = tid; idx < 2048; idx += 256) {
                const int o = idx & 127, m = idx >> 7;
                const float v = fmaxf(
                    fmaxf(bf2f(park[(2 * m) * 136 + o]), bf2f(park[(2 * m + 1) * 136 + o])),
                    fmaxf(bf2f(park[(32 + 2 * m) * 136 + o]), bf2f(park[(33 + 2 * m) * 136 + o])));
                phiT[((size_t)b * MM + mb + m) * CI + o] = f2bfbits(v);
            }
        } else {
            for (int idx = tid; idx < 2048; idx += 256) {
                const int o = idx >> 4, m = idx & 15;
                const float v = fmaxf(
                    fmaxf(bf2f(park[(2 * m) * 136 + o]), bf2f(park[(2 * m + 1) * 136 + o])),
                    fmaxf(bf2f(park[(32 + 2 * m) * 136 + o]), bf2f(park[(33 + 2 * m) * 136 + o])));
                gT[((size_t)b * CI + o) * MM + mb + m] = f2bfbits(v);
            }
        }
    }
}

// ---------------------------------------------------------------------------
// K2: flash attention, bf16 MFMA (unchanged from round 2)
// ---------------------------------------------------------------------------
__global__ __launch_bounds__(256, 2) void k_attn(
    const unsigned short* __restrict__ thetaT,
    const unsigned short* __restrict__ phiT,
    const unsigned short* __restrict__ gT,
    unsigned short* __restrict__ yp,
    float* __restrict__ mbuf, float* __restrict__ lbuf)
{
    __shared__ __align__(16) char smem[40960];
    const int tid  = threadIdx.x;
    const int wave = tid >> 6;
    const int lane = tid & 63;
    const int lq = lane & 15, G = lane >> 4;
    const int qblk = blockIdx.x, s = blockIdx.y, b = blockIdx.z;
    const int qbase = qblk * 128 + wave * 32;
    const int koff0 = s * KSPAN;

    bf16x8 tf[2][4];
#pragma unroll
    for (int qt = 0; qt < 2; ++qt) {
        const size_t row = (size_t)b * NN + qbase + qt * 16 + lq;
#pragma unroll
        for (int D = 0; D < 4; ++D)
            tf[qt][D] = *(const bf16x8*)(thetaT + row * CI + D * 32 + G * 8);
    }

    const char* phiSrc = (const char*)(phiT + (size_t)b * MM * CI);
    const char* gSrc   = (const char*)(gT   + (size_t)b * CI * MM);
    int pk[2], pco[2], gci[2];
#pragma unroll
    for (int i = 0; i < 2; ++i) {
        const int kr = i * 4 + (lane >> 4);
        pk[i]  = wave * 8 + kr;
        pco[i] = ((lane & 15) ^ (kr & 7)) << 4;
        gci[i] = wave * 32 + i * 16 + (lane >> 2);
    }
    const int gco = ((lane & 3) ^ ((lane >> 2) & 3)) << 4;

    auto STAGE = [&](int buf, int koff) {
        char* pl = smem + buf * 16384 + wave * 2048;
        char* gl = smem + buf * 16384 + 8192 + wave * 2048;
#pragma unroll
        for (int i = 0; i < 2; ++i) {
            gll16(phiSrc + (size_t)(koff + pk[i]) * 256 + pco[i], pl + i * 1024);
            gll16(gSrc + (size_t)gci[i] * 4096 + (size_t)koff * 2 + gco, gl + i * 1024);
        }
    };

    f32x4 yacc[2][8];
#pragma unroll
    for (int qt = 0; qt < 2; ++qt)
#pragma unroll
        for (int c = 0; c < 8; ++c) yacc[qt][c] = (f32x4){0.f, 0.f, 0.f, 0.f};
    float mreg[2] = {-1e30f, -1e30f};
    float lreg[2] = {0.f, 0.f};

    STAGE(0, koff0);
    __syncthreads();

    char* pP = smem + 32768 + wave * 2048;
    const int swq = (lq & 3) << 4;
    const int swk = (lq & 7) << 4;

    for (int t = 0; t < NTILES; ++t) {
        const int cur = t & 1;
        if (t < NTILES - 1) STAGE(cur ^ 1, koff0 + (t + 1) * KT);
        const char* pbuf = smem + cur * 16384;
        const char* gbuf = smem + cur * 16384 + 8192;

        f32x4 sacc[2][2];
#pragma unroll
        for (int qt = 0; qt < 2; ++qt)
#pragma unroll
            for (int ks = 0; ks < 2; ++ks) sacc[qt][ks] = (f32x4){0.f, 0.f, 0.f, 0.f};
#pragma unroll
        for (int D = 0; D < 4; ++D) {
            const int co = (((D * 4 + G) << 4) ^ swk);
            const bf16x8 a0 = *(const bf16x8*)(pbuf + lq * 256 + co);
            const bf16x8 a1 = *(const bf16x8*)(pbuf + (16 + lq) * 256 + co);
            sacc[0][0] = __builtin_amdgcn_mfma_f32_16x16x32_bf16(a0, tf[0][D], sacc[0][0], 0, 0, 0);
            sacc[1][0] = __builtin_amdgcn_mfma_f32_16x16x32_bf16(a0, tf[1][D], sacc[1][0], 0, 0, 0);
            sacc[0][1] = __builtin_amdgcn_mfma_f32_16x16x32_bf16(a1, tf[0][D], sacc[0][1], 0, 0, 0);
            sacc[1][1] = __builtin_amdgcn_mfma_f32_16x16x32_bf16(a1, tf[1][D], sacc[1][1], 0, 0, 0);
        }

#pragma unroll
        for (int qt = 0; qt < 2; ++qt) {
            float p[8];
            float mx = -1e30f;
#pragma unroll
            for (int ks = 0; ks < 2; ++ks)
#pragma unroll
                for (int r = 0; r < 4; ++r) mx = fmaxf(mx, sacc[qt][ks][r]);
            mx = fmaxf(mx, __shfl_xor(mx, 16));
            mx = fmaxf(mx, __shfl_xor(mx, 32));
            const float mnew = fmaxf(mreg[qt], mx);
            const float scale = __expf(mreg[qt] - mnew);
            float sum = 0.f;
#pragma unroll
            for (int ks = 0; ks < 2; ++ks)
#pragma unroll
                for (int r = 0; r < 4; ++r) {
                    const float e = __expf(sacc[qt][ks][r] - mnew);
                    p[ks * 4 + r] = e;
                    sum += e;
                }
            sum += __shfl_xor(sum, 16);
            sum += __shfl_xor(sum, 32);
            mreg[qt] = mnew;
            lreg[qt] = lreg[qt] * scale + sum;
#pragma unroll
            for (int c = 0; c < 8; ++c) yacc[qt][c] *= scale;
#pragma unroll
            for (int ks = 0; ks < 2; ++ks)
#pragma unroll
                for (int r2 = 0; r2 < 2; ++r2) {
                    const unsigned w = (unsigned)f2bfbits(p[ks * 4 + r2 * 2]) |
                                       ((unsigned)f2bfbits(p[ks * 4 + r2 * 2 + 1]) << 16);
                    const int byt = (ks * 32 + G * 8 + r2 * 4) ^ swq;
                    *(unsigned*)(pP + qt * 1024 + lq * 64 + byt) = w;
                }
        }

        bf16x8 pf[2];
#pragma unroll
        for (int qt = 0; qt < 2; ++qt)
            pf[qt] = *(const bf16x8*)(pP + qt * 1024 + lq * 64 + ((G * 16) ^ swq));
#pragma unroll
        for (int c = 0; c < 8; ++c) {
            const int row = c * 16 + lq;
            const bf16x8 gf = *(const bf16x8*)(gbuf + row * 64 + ((G * 16) ^ swq));
            yacc[0][c] = __builtin_amdgcn_mfma_f32_16x16x32_bf16(gf, pf[0], yacc[0][c], 0, 0, 0);
            yacc[1][c] = __builtin_amdgcn_mfma_f32_16x16x32_bf16(gf, pf[1], yacc[1][c], 0, 0, 0);
        }
        __syncthreads();
    }

    const int sb = b * NSPLIT + s;
    if (lane < 16) {
#pragma unroll
        for (int qt = 0; qt < 2; ++qt) {
            const int n = qbase + qt * 16 + lq;
            mbuf[(size_t)sb * NN + n] = mreg[qt];
            lbuf[(size_t)sb * NN + n] = lreg[qt];
        }
    }
#pragma unroll
    for (int qt = 0; qt < 2; ++qt) {
        const int n = qbase + qt * 16 + lq;
#pragma unroll
        for (int c = 0; c < 8; ++c)
#pragma unroll
            for (int r = 0; r < 4; ++r) {
                const int ci = c * 16 + G * 4 + r;
                yp[((size_t)sb * CI + ci) * NN + n] = f2bfbits(yacc[qt][c][r]);
            }
    }
}

// ---------------------------------------------------------------------------
// K2b: combine K-splits -> y bf16 [b][ci][n]
// ---------------------------------------------------------------------------
__global__ __launch_bounds__(256) void k_combine(
    const unsigned short* __restrict__ yp,
    const float* __restrict__ mbuf, const float* __restrict__ lbuf,
    unsigned short* __restrict__ y16)
{
    const int n = blockIdx.x * 256 + threadIdx.x;
    const int cc = blockIdx.y, b = blockIdx.z;
    float m[NSPLIT], l[NSPLIT];
#pragma unroll
    for (int s = 0; s < NSPLIT; ++s) {
        m[s] = mbuf[(size_t)(b * NSPLIT + s) * NN + n];
        l[s] = lbuf[(size_t)(b * NSPLIT + s) * NN + n];
    }
    const float mg = fmaxf(fmaxf(m[0], m[1]), fmaxf(m[2], m[3]));
    float w[NSPLIT], denom = 0.f;
#pragma unroll
    for (int s = 0; s < NSPLIT; ++s) { w[s] = __expf(m[s] - mg); denom += l[s] * w[s]; }
    const float inv = 1.f / denom;
#pragma unroll
    for (int i = 0; i < 16; ++i) {
        const int ci = cc * 16 + i;
        float acc = 0.f;
#pragma unroll
        for (int s = 0; s < NSPLIT; ++s)
            acc += bf2f(yp[((size_t)(b * NSPLIT + s) * CI + ci) * NN + n]) * w[s];
        y16[((size_t)b * CI + ci) * NN + n] = f2bfbits(acc * inv);
    }
}

// ---------------------------------------------------------------------------
// K3: output conv (bf16 in, fp32 weights, 128->256) + BN partial sums
// ---------------------------------------------------------------------------
__global__ __launch_bounds__(256) void k_outconv(
    const unsigned short* __restrict__ yin, const float* __restrict__ ow,
    const float* __restrict__ obias, float* __restrict__ y2,
    float* __restrict__ psum, float* __restrict__ psq)
{
    __shared__ float Ws[64 * 17];
    __shared__ float Xs[16 * 132];
    const int ntile = blockIdx.x, otile = blockIdx.y, b = blockIdx.z;
    const int obase = otile * 64, nbase = ntile * 128;
    const int tid = threadIdx.x, tx = tid & 15, ty = tid >> 4;
    const float* Wm = ow + obase * CI;
    const unsigned short* Xb = yin + (size_t)b * CI * NN;

    float acc[4][8];
#pragma unroll
    for (int i = 0; i < 4; ++i)
#pragma unroll
        for (int j = 0; j < 8; ++j) acc[i][j] = 0.f;

    const int kks = tid >> 4, n8 = (tid & 15) * 8;
    for (int c0 = 0; c0 < CI; c0 += 16) {
        __syncthreads();
        for (int idx = tid; idx < 1024; idx += 256) {
            const int o = idx >> 4, kk = idx & 15;
            Ws[o * 17 + kk] = Wm[o * CI + c0 + kk];
        }
        {
            const uint4 u = *(const uint4*)&Xb[(size_t)(c0 + kks) * NN + nbase + n8];
            float* xr = &Xs[kks * 132 + n8];
            xr[0] = __builtin_bit_cast(float, u.x << 16);
            xr[1] = __builtin_bit_cast(float, u.x & 0xffff0000u);
            xr[2] = __builtin_bit_cast(float, u.y << 16);
            xr[3] = __builtin_bit_cast(float, u.y & 0xffff0000u);
            xr[4] = __builtin_bit_cast(float, u.z << 16);
            xr[5] = __builtin_bit_cast(float, u.z & 0xffff0000u);
            xr[6] = __builtin_bit_cast(float, u.w << 16);
            xr[7] = __builtin_bit_cast(float, u.w & 0xffff0000u);
        }
        __syncthreads();
#pragma unroll
        for (int kk = 0; kk < 16; ++kk) {
            float xv[8], wv[4];
            *(float4*)&xv[0] = *(const float4*)&Xs[kk * 132 + tx * 8];
            *(float4*)&xv[4] = *(const float4*)&Xs[kk * 132 + tx * 8 + 4];
#pragma unroll
            for (int i = 0; i < 4; ++i) wv[i] = Ws[(ty * 4 + i) * 17 + kk];
#pragma unroll
            for (int i = 0; i < 4; ++i)
#pragma unroll
                for (int j = 0; j < 8; ++j)
                    acc[i][j] = fmaf(wv[i], xv[j], acc[i][j]);
        }
    }

#pragma unroll
    for (int i = 0; i < 4; ++i) {
        const float bv = obias[obase + ty * 4 + i];
#pragma unroll
        for (int j = 0; j < 8; ++j) acc[i][j] += bv;
    }
#pragma unroll
    for (int i = 0; i < 4; ++i) {
        const size_t base = ((size_t)b * CC + obase + ty * 4 + i) * NN + nbase + tx * 8;
        *(float4*)&y2[base]     = make_float4(acc[i][0], acc[i][1], acc[i][2], acc[i][3]);
        *(float4*)&y2[base + 4] = make_float4(acc[i][4], acc[i][5], acc[i][6], acc[i][7]);
    }
#pragma unroll
    for (int i = 0; i < 4; ++i) {
        float sv = 0.f, q = 0.f;
#pragma unroll
        for (int j = 0; j < 8; ++j) { sv += acc[i][j]; q += acc[i][j] * acc[i][j]; }
#pragma unroll
        for (int d = 1; d < 16; d <<= 1) { sv += __shfl_xor(sv, d); q += __shfl_xor(q, d); }
        if (tx == 0) {
            const int co = obase + ty * 4 + i;
            psum[co * 128 + b * 64 + ntile] = sv;
            psq [co * 128 + b * 64 + ntile] = q;
        }
    }
}

// K4: reduce partials -> mean, inv_std
__global__ void k_red(const float* __restrict__ psum, const float* __restrict__ psq,
                      float* __restrict__ stats)
{
    const int co = threadIdx.x;
    float s = 0.f, q = 0.f;
    for (int i = 0; i < 128; ++i) { s += psum[co * 128 + i]; q += psq[co * 128 + i]; }
    const float mean = s * (1.f / 16384.f);
    const float var = q * (1.f / 16384.f) - mean * mean;
    stats[co] = mean;
    stats[256 + co] = rsqrtf(var + 1e-5f);
}

// K5: out = x + bn(y2) ; y2 lives in d_out, in-place
__global__ __launch_bounds__(256) void k_bn(
    const float* __restrict__ x, const float* __restrict__ bw,
    const float* __restrict__ bb, const float* __restrict__ stats,
    float* __restrict__ out)
{
    const int i4 = blockIdx.x * 256 + threadIdx.x;
    const int c = (i4 >> 11) & 255;
    const float a = stats[256 + c] * bw[c];
    const float bias2 = bb[c] - stats[c] * a;
    const float4 v = ((const float4*)out)[i4];
    const float4 xv = ((const float4*)x)[i4];
    float4 r;
    r.x = xv.x + v.x * a + bias2;
    r.y = xv.y + v.y * a + bias2;
    r.z = xv.z + v.z * a + bias2;
    r.w = xv.w + v.w * a + bias2;
    ((float4*)out)[i4] = r;
}

extern "C" void kernel_launch(void* const* d_in, const int* in_sizes, int n_in,
                              void* d_out, int out_size, void* d_ws, size_t ws_size,
                              hipStream_t stream) {
    const float* x       = (const float*)d_in[0];
    const float* g_w     = (const float*)d_in[1];
    const float* g_b     = (const float*)d_in[2];
    const float* theta_w = (const float*)d_in[3];
    const float* theta_b = (const float*)d_in[4];
    const float* phi_w   = (const float*)d_in[5];
    const float* phi_b   = (const float*)d_in[6];
    const float* out_w   = (const float*)d_in[7];
    const float* out_b   = (const float*)d_in[8];
    const float* bn_w    = (const float*)d_in[9];
    const float* bn_b    = (const float*)d_in[10];

    char* ws = (char*)d_ws;
    unsigned short* xT      = (unsigned short*)(ws + OFF_XT);
    unsigned short* wqh     = (unsigned short*)(ws + OFF_WQH);
    unsigned short* wql     = (unsigned short*)(ws + OFF_WQL);
    unsigned short* woh     = (unsigned short*)(ws + OFF_WOH);
    unsigned short* wol     = (unsigned short*)(ws + OFF_WOL);
    unsigned short* theta16 = (unsigned short*)(ws + OFF_THETA16);
    unsigned short* phi16   = (unsigned short*)(ws + OFF_PHI16);
    unsigned short* g16     = (unsigned short*)(ws + OFF_G16);
    unsigned short* y16     = (unsigned short*)(ws + OFF_Y16);
    float* mbuf  = (float*)(ws + OFF_M);
    float* lbuf  = (float*)(ws + OFF_L);
    float* psum  = (float*)(ws + OFF_PSUM);
    float* psq   = (float*)(ws + OFF_PSQ);
    float* stats = (float*)(ws + OFF_STAT);
    float* out   = (float*)d_out;
    unsigned short* yp = (unsigned short*)d_out;

    k_prep<<<dim3(512), 256, 0, stream>>>(theta_w, phi_w, g_w, out_w, wqh, wql, woh, wol);
    k_xt<<<dim3(128, 4, 2), 256, 0, stream>>>(x, xT);
    k_qkvm<<<dim3(128, 3, 2), 256, 0, stream>>>(xT, wqh, wql, theta_b, phi_b, g_b,
                                                theta16, phi16, g16);
    k_attn<<<dim3(64, NSPLIT, 2), 256, 0, stream>>>(theta16, phi16, g16, yp, mbuf, lbuf);
    k_combine<<<dim3(32, 8, 2), 256, 0, stream>>>(yp, mbuf, lbuf, y16);
    k_outconv<<<dim3(64, 4, 2), 256, 0, stream>>>(y16, out_w, out_b, out, psum, psq);
    k_red<<<1, 256, 0, stream>>>(psum, psq, stats);
    k_bn<<<4096, 256, 0, stream>>>(x, bn_w, bn_b, stats, out);
}

// Round 4
// 118.166 us; speedup vs baseline: 5.3411x; 1.0084x over previous
//
#include <hip/hip_runtime.h>
#include <math.h>

#define CC 256
#define CI 128
#define NN 8192
#define MM 2048
#define NSPLIT 4
#define KSPAN 512
#define KT 32
#define NTILES 16
#define SUBC 20.0f

typedef __attribute__((ext_vector_type(8))) short bf16x8;
typedef __attribute__((ext_vector_type(4))) float f32x4;

// ws byte offsets
#define OFF_XT      0u
#define OFF_WQH     8388608u
#define OFF_WQL     8585216u
#define OFF_WOH     8781824u
#define OFF_WOL     8847360u
#define OFF_THETA16 8912896u
#define OFF_PHI16   13107200u
#define OFF_G16     14155776u
#define OFF_Y16     15204352u
#define OFF_L       19660800u
#define OFF_PSUM    19922944u
#define OFF_PSQ     20054016u
#define OFF_STAT    20185088u

static __device__ __forceinline__ unsigned short f2bfbits(float x) {
    unsigned u = __builtin_bit_cast(unsigned, x);
    u = u + 0x7fffu + ((u >> 16) & 1u);
    return (unsigned short)(u >> 16);
}
static __device__ __forceinline__ float bf2f(unsigned short h) {
    return __builtin_bit_cast(float, ((unsigned)h) << 16);
}
static __device__ __forceinline__ void gll16(const void* g, void* l) {
    __builtin_amdgcn_global_load_lds(
        (const __attribute__((address_space(1))) unsigned int*)g,
        (__attribute__((address_space(3))) unsigned int*)l, 16, 0, 0);
}

// ---------------------------------------------------------------------------
// K0a: weights -> bf16 hi/lo.  Wq = [theta;phi;g] stacked [384][256]; Wo [256][128]
// ---------------------------------------------------------------------------
__global__ __launch_bounds__(256) void k_prep(
    const float* __restrict__ tw, const float* __restrict__ pw,
    const float* __restrict__ gw, const float* __restrict__ ow,
    unsigned short* __restrict__ wqh, unsigned short* __restrict__ wql,
    unsigned short* __restrict__ woh, unsigned short* __restrict__ wol)
{
    const int i = blockIdx.x * 256 + threadIdx.x;
    if (i < 98304) {
        const float v = (i < 32768) ? tw[i] : (i < 65536) ? pw[i - 32768] : gw[i - 65536];
        const unsigned short h = f2bfbits(v);
        wqh[i] = h;
        wql[i] = f2bfbits(v - bf2f(h));
    } else {
        const int j = i - 98304;
        const float v = ow[j];
        const unsigned short h = f2bfbits(v);
        woh[j] = h;
        wol[j] = f2bfbits(v - bf2f(h));
    }
}

// ---------------------------------------------------------------------------
// K0b: x [b][256 c][8192 n] fp32 -> xT [b][n][256 c] bf16 (LDS transpose)
// ---------------------------------------------------------------------------
__global__ __launch_bounds__(256) void k_xt(const float* __restrict__ x,
                                            unsigned short* __restrict__ xT)
{
    __shared__ float Xl[64 * 68];
    const int nb = blockIdx.x * 64, cb = blockIdx.y * 64, b = blockIdx.z;
    const int t = threadIdx.x;
    const float* xb = x + ((size_t)b * CC + cb) * NN + nb;
    {
        const int cl = t >> 4, n4 = (t & 15) * 4;
#pragma unroll
        for (int i = 0; i < 4; ++i)
            *(float4*)&Xl[(cl + i * 16) * 68 + n4] =
                *(const float4*)&xb[(size_t)(cl + i * 16) * NN + n4];
    }
    __syncthreads();
    const int n = t >> 2, c0 = (t & 3) * 16;
    unsigned short v[16];
#pragma unroll
    for (int j = 0; j < 16; ++j) v[j] = f2bfbits(Xl[(c0 + j) * 68 + n]);
    unsigned short* dst = xT + ((size_t)b * NN + nb + n) * CC + cb + c0;
    *(uint4*)dst = *(uint4*)&v[0];
    *(uint4*)(dst + 8) = *(uint4*)&v[8];
}

// ---------------------------------------------------------------------------
// K1: theta/phi/g via bf16 MFMA, split-W (hi+lo)
// ---------------------------------------------------------------------------
__global__ __launch_bounds__(256) void k_qkvm(
    const unsigned short* __restrict__ xT,
    const unsigned short* __restrict__ wqh, const unsigned short* __restrict__ wql,
    const float* __restrict__ tb, const float* __restrict__ pb, const float* __restrict__ gb,
    unsigned short* __restrict__ thetaT, unsigned short* __restrict__ phiT,
    unsigned short* __restrict__ gT)
{
    __shared__ unsigned short park[64 * 136];
    const int nt_ = blockIdx.x, sel = blockIdx.y, b = blockIdx.z;
    const int nb = nt_ * 64;
    const int tid = threadIdx.x, wave = tid >> 6, lane = tid & 63;
    const int lq = lane & 15, G = lane >> 4;
    const int obase = wave * 32;
    const int orow = sel * 128 + obase;
    const float* bias = (sel == 0) ? tb : (sel == 1) ? pb : gb;

    f32x4 acc[2][4];
#pragma unroll
    for (int ot = 0; ot < 2; ++ot)
#pragma unroll
        for (int nt = 0; nt < 4; ++nt) acc[ot][nt] = (f32x4){0.f, 0.f, 0.f, 0.f};

    const unsigned short* xrow = xT + ((size_t)b * NN + nb) * CC;
#pragma unroll
    for (int kc = 0; kc < 8; ++kc) {
        bf16x8 wh[2], wl[2], xf[4];
#pragma unroll
        for (int ot = 0; ot < 2; ++ot) {
            const size_t wr = (size_t)(orow + ot * 16 + lq) * CC + kc * 32 + G * 8;
            wh[ot] = *(const bf16x8*)(wqh + wr);
            wl[ot] = *(const bf16x8*)(wql + wr);
        }
#pragma unroll
        for (int nt = 0; nt < 4; ++nt)
            xf[nt] = *(const bf16x8*)(xrow + (size_t)(nt * 16 + lq) * CC + kc * 32 + G * 8);
#pragma unroll
        for (int ot = 0; ot < 2; ++ot)
#pragma unroll
            for (int nt = 0; nt < 4; ++nt) {
                acc[ot][nt] = __builtin_amdgcn_mfma_f32_16x16x32_bf16(wh[ot], xf[nt], acc[ot][nt], 0, 0, 0);
                acc[ot][nt] = __builtin_amdgcn_mfma_f32_16x16x32_bf16(wl[ot], xf[nt], acc[ot][nt], 0, 0, 0);
            }
    }
#pragma unroll
    for (int ot = 0; ot < 2; ++ot) {
        const float4 bv = *(const float4*)&bias[obase + ot * 16 + G * 4];
#pragma unroll
        for (int nt = 0; nt < 4; ++nt) {
            acc[ot][nt][0] += bv.x; acc[ot][nt][1] += bv.y;
            acc[ot][nt][2] += bv.z; acc[ot][nt][3] += bv.w;
        }
    }

    if (sel == 0) {
#pragma unroll
        for (int ot = 0; ot < 2; ++ot)
#pragma unroll
            for (int nt = 0; nt < 4; ++nt) {
                unsigned short pk[4];
#pragma unroll
                for (int r = 0; r < 4; ++r) pk[r] = f2bfbits(acc[ot][nt][r]);
                const int n = nb + nt * 16 + lq;
                const int ci = obase + ot * 16 + G * 4;
                *(uint2*)&thetaT[((size_t)b * NN + n) * CI + ci] = *(uint2*)pk;
            }
    } else {
#pragma unroll
        for (int ot = 0; ot < 2; ++ot)
#pragma unroll
            for (int nt = 0; nt < 4; ++nt) {
                unsigned short pk[4];
#pragma unroll
                for (int r = 0; r < 4; ++r) pk[r] = f2bfbits(acc[ot][nt][r]);
                const int n = nt * 16 + lq;
                const int o = obase + ot * 16 + G * 4;
                *(uint2*)&park[n * 136 + o] = *(uint2*)pk;
            }
        __syncthreads();
        const int tfrm = nb >> 10, h0 = (nb >> 5) & 31;
        const int mb = tfrm * 256 + (h0 >> 1) * 16;
        if (sel == 1) {
            for (int idx = tid; idx < 2048; idx += 256) {
                const int o = idx & 127, m = idx >> 7;
                const float v = fmaxf(
                    fmaxf(bf2f(park[(2 * m) * 136 + o]), bf2f(park[(2 * m + 1) * 136 + o])),
                    fmaxf(bf2f(park[(32 + 2 * m) * 136 + o]), bf2f(park[(33 + 2 * m) * 136 + o])));
                phiT[((size_t)b * MM + mb + m) * CI + o] = f2bfbits(v);
            }
        } else {
            for (int idx = tid; idx < 2048; idx += 256) {
                const int o = idx >> 4, m = idx & 15;
                const float v = fmaxf(
                    fmaxf(bf2f(park[(2 * m) * 136 + o]), bf2f(park[(2 * m + 1) * 136 + o])),
                    fmaxf(bf2f(park[(32 + 2 * m) * 136 + o]), bf2f(park[(33 + 2 * m) * 136 + o])));
                gT[((size_t)b * CI + o) * MM + mb + m] = f2bfbits(v);
            }
        }
    }
}

// ---------------------------------------------------------------------------
// K2: flash attention, static-max softmax (p = exp(s - SUBC), exact up to a
// constant factor that cancels in y/l). grid (128 qblk, NSPLIT, 2 b), 4 waves,
// each wave 16 queries. Per-lane l accumulated across tiles, reduced once.
// ---------------------------------------------------------------------------
__global__ __launch_bounds__(256, 4) void k_attn(
    const unsigned short* __restrict__ thetaT,
    const unsigned short* __restrict__ phiT,
    const unsigned short* __restrict__ gT,
    unsigned short* __restrict__ yp,
    float* __restrict__ lbuf)
{
    __shared__ __align__(16) char smem[36864];   // 2x(8K phi + 8K g) + 4K P
    const int tid  = threadIdx.x;
    const int wave = tid >> 6;
    const int lane = tid & 63;
    const int lq = lane & 15, G = lane >> 4;
    const int qblk = blockIdx.x, s = blockIdx.y, b = blockIdx.z;
    const int qbase = qblk * 64 + wave * 16;
    const int koff0 = s * KSPAN;

    // theta fragments (B-operand of S^T), 16 queries per wave
    bf16x8 tf[4];
    {
        const size_t row = (size_t)b * NN + qbase + lq;
#pragma unroll
        for (int D = 0; D < 4; ++D)
            tf[D] = *(const bf16x8*)(thetaT + row * CI + D * 32 + G * 8);
    }

    const char* phiSrc = (const char*)(phiT + (size_t)b * MM * CI);
    const char* gSrc   = (const char*)(gT   + (size_t)b * CI * MM);
    int pk[2], pco[2], gci[2];
#pragma unroll
    for (int i = 0; i < 2; ++i) {
        const int kr = i * 4 + (lane >> 4);
        pk[i]  = wave * 8 + kr;
        pco[i] = ((lane & 15) ^ (kr & 7)) << 4;
        gci[i] = wave * 32 + i * 16 + (lane >> 2);
    }
    const int gco = ((lane & 3) ^ ((lane >> 2) & 3)) << 4;

    auto STAGE = [&](int buf, int koff) {
        char* pl = smem + buf * 16384 + wave * 2048;
        char* gl = smem + buf * 16384 + 8192 + wave * 2048;
#pragma unroll
        for (int i = 0; i < 2; ++i) {
            gll16(phiSrc + (size_t)(koff + pk[i]) * 256 + pco[i], pl + i * 1024);
            gll16(gSrc + (size_t)gci[i] * 4096 + (size_t)koff * 2 + gco, gl + i * 1024);
        }
    };

    f32x4 yacc[8];
#pragma unroll
    for (int c = 0; c < 8; ++c) yacc[c] = (f32x4){0.f, 0.f, 0.f, 0.f};
    float lreg = 0.f;

    STAGE(0, koff0);
    __syncthreads();

    char* pP = smem + 32768 + wave * 1024;
    const int swq = (lq & 3) << 4;
    const int swk = (lq & 7) << 4;

    for (int t = 0; t < NTILES; ++t) {
        const int cur = t & 1;
        if (t < NTILES - 1) STAGE(cur ^ 1, koff0 + (t + 1) * KT);
        const char* pbuf = smem + cur * 16384;
        const char* gbuf = smem + cur * 16384 + 8192;

        // S^T = phi * theta^T  (2 k-subtiles x 1 q-tile)
        f32x4 sacc[2];
        sacc[0] = (f32x4){0.f, 0.f, 0.f, 0.f};
        sacc[1] = (f32x4){0.f, 0.f, 0.f, 0.f};
#pragma unroll
        for (int D = 0; D < 4; ++D) {
            const int co = (((D * 4 + G) << 4) ^ swk);
            const bf16x8 a0 = *(const bf16x8*)(pbuf + lq * 256 + co);
            const bf16x8 a1 = *(const bf16x8*)(pbuf + (16 + lq) * 256 + co);
            sacc[0] = __builtin_amdgcn_mfma_f32_16x16x32_bf16(a0, tf[D], sacc[0], 0, 0, 0);
            sacc[1] = __builtin_amdgcn_mfma_f32_16x16x32_bf16(a1, tf[D], sacc[1], 0, 0, 0);
        }

        // static-max exp + local l accumulation + P pack (no rescale, no shuffles)
        float p[8];
#pragma unroll
        for (int ks = 0; ks < 2; ++ks)
#pragma unroll
            for (int r = 0; r < 4; ++r) {
                const float e = __expf(sacc[ks][r] - SUBC);
                p[ks * 4 + r] = e;
                lreg += e;
            }
#pragma unroll
        for (int ks = 0; ks < 2; ++ks)
#pragma unroll
            for (int r2 = 0; r2 < 2; ++r2) {
                const unsigned w = (unsigned)f2bfbits(p[ks * 4 + r2 * 2]) |
                                   ((unsigned)f2bfbits(p[ks * 4 + r2 * 2 + 1]) << 16);
                const int byt = (ks * 32 + G * 8 + r2 * 4) ^ swq;
                *(unsigned*)(pP + lq * 64 + byt) = w;
            }

        // PV: y^T += g^T * P^T
        const bf16x8 pf = *(const bf16x8*)(pP + lq * 64 + ((G * 16) ^ swq));
#pragma unroll
        for (int c = 0; c < 8; ++c) {
            const int row = c * 16 + lq;
            const bf16x8 gf = *(const bf16x8*)(gbuf + row * 64 + ((G * 16) ^ swq));
            yacc[c] = __builtin_amdgcn_mfma_f32_16x16x32_bf16(gf, pf, yacc[c], 0, 0, 0);
        }
        __syncthreads();
    }

    // final l reduce across the 4 G-groups (each covers a disjoint key subset)
    lreg += __shfl_xor(lreg, 16);
    lreg += __shfl_xor(lreg, 32);

    const int sb = b * NSPLIT + s;
    if (lane < 16) lbuf[(size_t)sb * NN + qbase + lq] = lreg;
#pragma unroll
    for (int c = 0; c < 8; ++c)
#pragma unroll
        for (int r = 0; r < 4; ++r) {
            const int ci = c * 16 + G * 4 + r;
            yp[((size_t)sb * CI + ci) * NN + qbase + lq] = f2bfbits(yacc[c][r]);
        }
}

// ---------------------------------------------------------------------------
// K2b: combine K-splits -> y bf16 [b][ci][n].  Linear combine (shared max).
// ---------------------------------------------------------------------------
__global__ __launch_bounds__(256) void k_combine(
    const unsigned short* __restrict__ yp,
    const float* __restrict__ lbuf,
    unsigned short* __restrict__ y16)
{
    const int n = blockIdx.x * 256 + threadIdx.x;
    const int cc = blockIdx.y, b = blockIdx.z;
    float l = 0.f;
#pragma unroll
    for (int s = 0; s < NSPLIT; ++s) l += lbuf[(size_t)(b * NSPLIT + s) * NN + n];
    const float inv = 1.f / l;
#pragma unroll
    for (int i = 0; i < 16; ++i) {
        const int ci = cc * 16 + i;
        float acc = 0.f;
#pragma unroll
        for (int s = 0; s < NSPLIT; ++s)
            acc += bf2f(yp[((size_t)(b * NSPLIT + s) * CI + ci) * NN + n]);
        y16[((size_t)b * CI + ci) * NN + n] = f2bfbits(acc * inv);
    }
}

// ---------------------------------------------------------------------------
// K3: output conv (bf16 in, fp32 weights, 128->256) + BN partial sums
// ---------------------------------------------------------------------------
__global__ __launch_bounds__(256) void k_outconv(
    const unsigned short* __restrict__ yin, const float* __restrict__ ow,
    const float* __restrict__ obias, float* __restrict__ y2,
    float* __restrict__ psum, float* __restrict__ psq)
{
    __shared__ float Ws[64 * 17];
    __shared__ float Xs[16 * 132];
    const int ntile = blockIdx.x, otile = blockIdx.y, b = blockIdx.z;
    const int obase = otile * 64, nbase = ntile * 128;
    const int tid = threadIdx.x, tx = tid & 15, ty = tid >> 4;
    const float* Wm = ow + obase * CI;
    const unsigned short* Xb = yin + (size_t)b * CI * NN;

    float acc[4][8];
#pragma unroll
    for (int i = 0; i < 4; ++i)
#pragma unroll
        for (int j = 0; j < 8; ++j) acc[i][j] = 0.f;

    const int kks = tid >> 4, n8 = (tid & 15) * 8;
    for (int c0 = 0; c0 < CI; c0 += 16) {
        __syncthreads();
        for (int idx = tid; idx < 1024; idx += 256) {
            const int o = idx >> 4, kk = idx & 15;
            Ws[o * 17 + kk] = Wm[o * CI + c0 + kk];
        }
        {
            const uint4 u = *(const uint4*)&Xb[(size_t)(c0 + kks) * NN + nbase + n8];
            float* xr = &Xs[kks * 132 + n8];
            xr[0] = __builtin_bit_cast(float, u.x << 16);
            xr[1] = __builtin_bit_cast(float, u.x & 0xffff0000u);
            xr[2] = __builtin_bit_cast(float, u.y << 16);
            xr[3] = __builtin_bit_cast(float, u.y & 0xffff0000u);
            xr[4] = __builtin_bit_cast(float, u.z << 16);
            xr[5] = __builtin_bit_cast(float, u.z & 0xffff0000u);
            xr[6] = __builtin_bit_cast(float, u.w << 16);
            xr[7] = __builtin_bit_cast(float, u.w & 0xffff0000u);
        }
        __syncthreads();
#pragma unroll
        for (int kk = 0; kk < 16; ++kk) {
            float xv[8], wv[4];
            *(float4*)&xv[0] = *(const float4*)&Xs[kk * 132 + tx * 8];
            *(float4*)&xv[4] = *(const float4*)&Xs[kk * 132 + tx * 8 + 4];
#pragma unroll
            for (int i = 0; i < 4; ++i) wv[i] = Ws[(ty * 4 + i) * 17 + kk];
#pragma unroll
            for (int i = 0; i < 4; ++i)
#pragma unroll
                for (int j = 0; j < 8; ++j)
                    acc[i][j] = fmaf(wv[i], xv[j], acc[i][j]);
        }
    }

#pragma unroll
    for (int i = 0; i < 4; ++i) {
        const float bv = obias[obase + ty * 4 + i];
#pragma unroll
        for (int j = 0; j < 8; ++j) acc[i][j] += bv;
    }
#pragma unroll
    for (int i = 0; i < 4; ++i) {
        const size_t base = ((size_t)b * CC + obase + ty * 4 + i) * NN + nbase + tx * 8;
        *(float4*)&y2[base]     = make_float4(acc[i][0], acc[i][1], acc[i][2], acc[i][3]);
        *(float4*)&y2[base + 4] = make_float4(acc[i][4], acc[i][5], acc[i][6], acc[i][7]);
    }
#pragma unroll
    for (int i = 0; i < 4; ++i) {
        float sv = 0.f, q = 0.f;
#pragma unroll
        for (int j = 0; j < 8; ++j) { sv += acc[i][j]; q += acc[i][j] * acc[i][j]; }
#pragma unroll
        for (int d = 1; d < 16; d <<= 1) { sv += __shfl_xor(sv, d); q += __shfl_xor(q, d); }
        if (tx == 0) {
            const int co = obase + ty * 4 + i;
            psum[co * 128 + b * 64 + ntile] = sv;
            psq [co * 128 + b * 64 + ntile] = q;
        }
    }
}

// K4: reduce partials -> mean, inv_std
__global__ void k_red(const float* __restrict__ psum, const float* __restrict__ psq,
                      float* __restrict__ stats)
{
    const int co = threadIdx.x;
    float s = 0.f, q = 0.f;
    for (int i = 0; i < 128; ++i) { s += psum[co * 128 + i]; q += psq[co * 128 + i]; }
    const float mean = s * (1.f / 16384.f);
    const float var = q * (1.f / 16384.f) - mean * mean;
    stats[co] = mean;
    stats[256 + co] = rsqrtf(var + 1e-5f);
}

// K5: out = x + bn(y2) ; y2 lives in d_out, in-place
__global__ __launch_bounds__(256) void k_bn(
    const float* __restrict__ x, const float* __restrict__ bw,
    const float* __restrict__ bb, const float* __restrict__ stats,
    float* __restrict__ out)
{
    const int i4 = blockIdx.x * 256 + threadIdx.x;
    const int c = (i4 >> 11) & 255;
    const float a = stats[256 + c] * bw[c];
    const float bias2 = bb[c] - stats[c] * a;
    const float4 v = ((const float4*)out)[i4];
    const float4 xv = ((const float4*)x)[i4];
    float4 r;
    r.x = xv.x + v.x * a + bias2;
    r.y = xv.y + v.y * a + bias2;
    r.z = xv.z + v.z * a + bias2;
    r.w = xv.w + v.w * a + bias2;
    ((float4*)out)[i4] = r;
}

extern "C" void kernel_launch(void* const* d_in, const int* in_sizes, int n_in,
                              void* d_out, int out_size, void* d_ws, size_t ws_size,
                              hipStream_t stream) {
    const float* x       = (const float*)d_in[0];
    const float* g_w     = (const float*)d_in[1];
    const float* g_b     = (const float*)d_in[2];
    const float* theta_w = (const float*)d_in[3];
    const float* theta_b = (const float*)d_in[4];
    const float* phi_w   = (const float*)d_in[5];
    const float* phi_b   = (const float*)d_in[6];
    const float* out_w   = (const float*)d_in[7];
    const float* out_b   = (const float*)d_in[8];
    const float* bn_w    = (const float*)d_in[9];
    const float* bn_b    = (const float*)d_in[10];

    char* ws = (char*)d_ws;
    unsigned short* xT      = (unsigned short*)(ws + OFF_XT);
    unsigned short* wqh     = (unsigned short*)(ws + OFF_WQH);
    unsigned short* wql     = (unsigned short*)(ws + OFF_WQL);
    unsigned short* woh     = (unsigned short*)(ws + OFF_WOH);
    unsigned short* wol     = (unsigned short*)(ws + OFF_WOL);
    unsigned short* theta16 = (unsigned short*)(ws + OFF_THETA16);
    unsigned short* phi16   = (unsigned short*)(ws + OFF_PHI16);
    unsigned short* g16     = (unsigned short*)(ws + OFF_G16);
    unsigned short* y16     = (unsigned short*)(ws + OFF_Y16);
    float* lbuf  = (float*)(ws + OFF_L);
    float* psum  = (float*)(ws + OFF_PSUM);
    float* psq   = (float*)(ws + OFF_PSQ);
    float* stats = (float*)(ws + OFF_STAT);
    float* out   = (float*)d_out;
    unsigned short* yp = (unsigned short*)d_out;

    k_prep<<<dim3(512), 256, 0, stream>>>(theta_w, phi_w, g_w, out_w, wqh, wql, woh, wol);
    k_xt<<<dim3(128, 4, 2), 256, 0, stream>>>(x, xT);
    k_qkvm<<<dim3(128, 3, 2), 256, 0, stream>>>(xT, wqh, wql, theta_b, phi_b, g_b,
                                                theta16, phi16, g16);
    k_attn<<<dim3(128, NSPLIT, 2), 256, 0, stream>>>(theta16, phi16, g16, yp, lbuf);
    k_combine<<<dim3(32, 8, 2), 256, 0, stream>>>(yp, lbuf, y16);
    k_outconv<<<dim3(64, 4, 2), 256, 0, stream>>>(y16, out_w, out_b, out, psum, psq);
    k_red<<<1, 256, 0, stream>>>(psum, psq, stats);
    k_bn<<<4096, 256, 0, stream>>>(x, bn_w, bn_b, stats, out);
}

// Round 5
// 114.876 us; speedup vs baseline: 5.4941x; 1.0286x over previous
//
#include <hip/hip_runtime.h>
#include <math.h>

#define CC 256
#define CI 128
#define NN 8192
#define MM 2048
#define NSPLIT 2
#define KSPAN 1024
#define KT 64
#define NCH 16
#define SUBC 20.0f

typedef __attribute__((ext_vector_type(8))) short bf16x8;
typedef __attribute__((ext_vector_type(4))) float f32x4;

// ws byte offsets
#define OFF_XT      0u
#define OFF_WQH     8388608u
#define OFF_WQL     8585216u
#define OFF_WOH     8781824u
#define OFF_WOL     8847360u
#define OFF_THETA16 8912896u
#define OFF_PHI16   13107200u
#define OFF_G16     14155776u
#define OFF_YT16    15204352u
#define OFF_YP      19398656u
#define OFF_LBUF    27787264u
#define OFF_PSUM    27918336u
#define OFF_PSQ     28180480u
#define OFF_STAT    28442624u

static __device__ __forceinline__ unsigned short f2bfbits(float x) {
    unsigned u = __builtin_bit_cast(unsigned, x);
    u = u + 0x7fffu + ((u >> 16) & 1u);
    return (unsigned short)(u >> 16);
}
static __device__ __forceinline__ float bf2f(unsigned short h) {
    return __builtin_bit_cast(float, ((unsigned)h) << 16);
}
static __device__ __forceinline__ void gll16(const void* g, void* l) {
    __builtin_amdgcn_global_load_lds(
        (const __attribute__((address_space(1))) unsigned int*)g,
        (__attribute__((address_space(3))) unsigned int*)l, 16, 0, 0);
}

// ---------------------------------------------------------------------------
// K0a: weights -> bf16 hi/lo
// ---------------------------------------------------------------------------
__global__ __launch_bounds__(256) void k_prep(
    const float* __restrict__ tw, const float* __restrict__ pw,
    const float* __restrict__ gw, const float* __restrict__ ow,
    unsigned short* __restrict__ wqh, unsigned short* __restrict__ wql,
    unsigned short* __restrict__ woh, unsigned short* __restrict__ wol)
{
    const int i = blockIdx.x * 256 + threadIdx.x;
    if (i < 98304) {
        const float v = (i < 32768) ? tw[i] : (i < 65536) ? pw[i - 32768] : gw[i - 65536];
        const unsigned short h = f2bfbits(v);
        wqh[i] = h;
        wql[i] = f2bfbits(v - bf2f(h));
    } else {
        const int j = i - 98304;
        const float v = ow[j];
        const unsigned short h = f2bfbits(v);
        woh[j] = h;
        wol[j] = f2bfbits(v - bf2f(h));
    }
}

// ---------------------------------------------------------------------------
// K0b: x fp32 [b][c][n] -> xT bf16 [b][n][c]
// ---------------------------------------------------------------------------
__global__ __launch_bounds__(256) void k_xt(const float* __restrict__ x,
                                            unsigned short* __restrict__ xT)
{
    __shared__ float Xl[64 * 68];
    const int nb = blockIdx.x * 64, cb = blockIdx.y * 64, b = blockIdx.z;
    const int t = threadIdx.x;
    const float* xb = x + ((size_t)b * CC + cb) * NN + nb;
    {
        const int cl = t >> 4, n4 = (t & 15) * 4;
#pragma unroll
        for (int i = 0; i < 4; ++i)
            *(float4*)&Xl[(cl + i * 16) * 68 + n4] =
                *(const float4*)&xb[(size_t)(cl + i * 16) * NN + n4];
    }
    __syncthreads();
    const int n = t >> 2, c0 = (t & 3) * 16;
    unsigned short v[16];
#pragma unroll
    for (int j = 0; j < 16; ++j) v[j] = f2bfbits(Xl[(c0 + j) * 68 + n]);
    unsigned short* dst = xT + ((size_t)b * NN + nb + n) * CC + cb + c0;
    *(uint4*)dst = *(uint4*)&v[0];
    *(uint4*)(dst + 8) = *(uint4*)&v[8];
}

// ---------------------------------------------------------------------------
// K1: theta/phi/g via bf16 MFMA, split-W
// ---------------------------------------------------------------------------
__global__ __launch_bounds__(256) void k_qkvm(
    const unsigned short* __restrict__ xT,
    const unsigned short* __restrict__ wqh, const unsigned short* __restrict__ wql,
    const float* __restrict__ tb, const float* __restrict__ pb, const float* __restrict__ gb,
    unsigned short* __restrict__ thetaT, unsigned short* __restrict__ phiT,
    unsigned short* __restrict__ gT)
{
    __shared__ unsigned short park[64 * 136];
    const int nt_ = blockIdx.x, sel = blockIdx.y, b = blockIdx.z;
    const int nb = nt_ * 64;
    const int tid = threadIdx.x, wave = tid >> 6, lane = tid & 63;
    const int lq = lane & 15, G = lane >> 4;
    const int obase = wave * 32;
    const int orow = sel * 128 + obase;
    const float* bias = (sel == 0) ? tb : (sel == 1) ? pb : gb;

    f32x4 acc[2][4];
#pragma unroll
    for (int ot = 0; ot < 2; ++ot)
#pragma unroll
        for (int nt = 0; nt < 4; ++nt) acc[ot][nt] = (f32x4){0.f, 0.f, 0.f, 0.f};

    const unsigned short* xrow = xT + ((size_t)b * NN + nb) * CC;
#pragma unroll
    for (int kc = 0; kc < 8; ++kc) {
        bf16x8 wh[2], wl[2], xf[4];
#pragma unroll
        for (int ot = 0; ot < 2; ++ot) {
            const size_t wr = (size_t)(orow + ot * 16 + lq) * CC + kc * 32 + G * 8;
            wh[ot] = *(const bf16x8*)(wqh + wr);
            wl[ot] = *(const bf16x8*)(wql + wr);
        }
#pragma unroll
        for (int nt = 0; nt < 4; ++nt)
            xf[nt] = *(const bf16x8*)(xrow + (size_t)(nt * 16 + lq) * CC + kc * 32 + G * 8);
#pragma unroll
        for (int ot = 0; ot < 2; ++ot)
#pragma unroll
            for (int nt = 0; nt < 4; ++nt) {
                acc[ot][nt] = __builtin_amdgcn_mfma_f32_16x16x32_bf16(wh[ot], xf[nt], acc[ot][nt], 0, 0, 0);
                acc[ot][nt] = __builtin_amdgcn_mfma_f32_16x16x32_bf16(wl[ot], xf[nt], acc[ot][nt], 0, 0, 0);
            }
    }
#pragma unroll
    for (int ot = 0; ot < 2; ++ot) {
        const float4 bv = *(const float4*)&bias[obase + ot * 16 + G * 4];
#pragma unroll
        for (int nt = 0; nt < 4; ++nt) {
            acc[ot][nt][0] += bv.x; acc[ot][nt][1] += bv.y;
            acc[ot][nt][2] += bv.z; acc[ot][nt][3] += bv.w;
        }
    }

    if (sel == 0) {
#pragma unroll
        for (int ot = 0; ot < 2; ++ot)
#pragma unroll
            for (int nt = 0; nt < 4; ++nt) {
                unsigned short pk[4];
#pragma unroll
                for (int r = 0; r < 4; ++r) pk[r] = f2bfbits(acc[ot][nt][r]);
                const int n = nb + nt * 16 + lq;
                const int ci = obase + ot * 16 + G * 4;
                *(uint2*)&thetaT[((size_t)b * NN + n) * CI + ci] = *(uint2*)pk;
            }
    } else {
#pragma unroll
        for (int ot = 0; ot < 2; ++ot)
#pragma unroll
            for (int nt = 0; nt < 4; ++nt) {
                unsigned short pk[4];
#pragma unroll
                for (int r = 0; r < 4; ++r) pk[r] = f2bfbits(acc[ot][nt][r]);
                const int n = nt * 16 + lq;
                const int o = obase + ot * 16 + G * 4;
                *(uint2*)&park[n * 136 + o] = *(uint2*)pk;
            }
        __syncthreads();
        const int tfrm = nb >> 10, h0 = (nb >> 5) & 31;
        const int mb = tfrm * 256 + (h0 >> 1) * 16;
        if (sel == 1) {
            for (int idx = tid; idx < 2048; idx += 256) {
                const int o = idx & 127, m = idx >> 7;
                const float v = fmaxf(
                    fmaxf(bf2f(park[(2 * m) * 136 + o]), bf2f(park[(2 * m + 1) * 136 + o])),
                    fmaxf(bf2f(park[(32 + 2 * m) * 136 + o]), bf2f(park[(33 + 2 * m) * 136 + o])));
                phiT[((size_t)b * MM + mb + m) * CI + o] = f2bfbits(v);
            }
        } else {
            for (int idx = tid; idx < 2048; idx += 256) {
                const int o = idx >> 4, m = idx & 15;
                const float v = fmaxf(
                    fmaxf(bf2f(park[(2 * m) * 136 + o]), bf2f(park[(2 * m + 1) * 136 + o])),
                    fmaxf(bf2f(park[(32 + 2 * m) * 136 + o]), bf2f(park[(33 + 2 * m) * 136 + o])));
                gT[((size_t)b * CI + o) * MM + mb + m] = f2bfbits(v);
            }
        }
    }
}

// ---------------------------------------------------------------------------
// K2: flash attention, static-max. grid (64 qblk, 2 s, 2 b), 512 thr = 8 waves.
// Each wave: 16 queries. Block iterates 16 chunks of KT=64 keys, chunk staged
// whole into LDS (double-buffered), 1 barrier per chunk.
// ---------------------------------------------------------------------------
__global__ __launch_bounds__(512, 4) void k_attn(
    const unsigned short* __restrict__ thetaT,
    const unsigned short* __restrict__ phiT,
    const unsigned short* __restrict__ gT,
    unsigned short* __restrict__ yp,
    float* __restrict__ lbuf)
{
    __shared__ __align__(16) char smem[73728];  // 2 x (phi 16K + g 16K) + P 8K
    const int tid  = threadIdx.x;
    const int wave = tid >> 6;
    const int lane = tid & 63;
    const int lq = lane & 15, G = lane >> 4;
    const int qblk = blockIdx.x, s = blockIdx.y, b = blockIdx.z;
    const int qbase = qblk * 128 + wave * 16;
    const int koff0 = s * KSPAN;

    // theta fragments (B-operand of S^T)
    bf16x8 tf[4];
    {
        const size_t row = (size_t)b * NN + qbase + lq;
#pragma unroll
        for (int D = 0; D < 4; ++D)
            tf[D] = *(const bf16x8*)(thetaT + row * CI + D * 32 + G * 8);
    }

    const char* phiSrc = (const char*)(phiT + (size_t)b * MM * CI);
    const char* gSrc   = (const char*)(gT   + (size_t)b * CI * MM);
    // phi chunk [64 k][256B], wave stages rows wave*8..+8, 2 issues x 4 rows
    int pk[2], pco[2];
#pragma unroll
    for (int i = 0; i < 2; ++i) {
        pk[i]  = wave * 8 + i * 4 + (lane >> 4);
        pco[i] = ((lane & 15) ^ (pk[i] & 7)) << 4;
    }
    // g chunk [128 ci][128B = 64 k], wave stages rows wave*16..+16, 2 issues x 8 rows
    const int gr0 = wave * 16 + (lane >> 3);      // +i*8
    const int u_   = lane & 7;
    const int gu  = (u_ & 4) | ((u_ & 3) ^ (gr0 & 3));  // (gr&3) identical for both issues

    auto STAGE = [&](int buf, int koff) {
        char* pl = smem + buf * 32768 + wave * 2048;
        char* gl = smem + buf * 32768 + 16384 + wave * 2048;
#pragma unroll
        for (int i = 0; i < 2; ++i) {
            gll16(phiSrc + (size_t)(koff + pk[i]) * 256 + pco[i], pl + i * 1024);
            gll16(gSrc + (size_t)(gr0 + i * 8) * 4096 + (size_t)koff * 2 + gu * 16, gl + i * 1024);
        }
    };

    f32x4 yacc[8];
#pragma unroll
    for (int c = 0; c < 8; ++c) yacc[c] = (f32x4){0.f, 0.f, 0.f, 0.f};
    float lreg = 0.f;

    STAGE(0, koff0);
    __syncthreads();

    char* pP = smem + 65536 + wave * 1024;
    const int swq = (lq & 3) << 4;
    const int swk = (lq & 7) << 4;

    for (int ch = 0; ch < NCH; ++ch) {
        const int cur = ch & 1;
        if (ch < NCH - 1) STAGE(cur ^ 1, koff0 + (ch + 1) * KT);
        const char* pbuf = smem + cur * 32768;
        const char* gbuf = smem + cur * 32768 + 16384;

#pragma unroll
        for (int t2 = 0; t2 < 2; ++t2) {   // two 32-key tiles per chunk
            // S^T = phi * theta^T
            f32x4 sacc[2];
            sacc[0] = (f32x4){0.f, 0.f, 0.f, 0.f};
            sacc[1] = (f32x4){0.f, 0.f, 0.f, 0.f};
#pragma unroll
            for (int D = 0; D < 4; ++D) {
                const int co = (((D * 4 + G) << 4) ^ swk);
                const bf16x8 a0 = *(const bf16x8*)(pbuf + (t2 * 32 + lq) * 256 + co);
                const bf16x8 a1 = *(const bf16x8*)(pbuf + (t2 * 32 + 16 + lq) * 256 + co);
                sacc[0] = __builtin_amdgcn_mfma_f32_16x16x32_bf16(a0, tf[D], sacc[0], 0, 0, 0);
                sacc[1] = __builtin_amdgcn_mfma_f32_16x16x32_bf16(a1, tf[D], sacc[1], 0, 0, 0);
            }

            // static-max exp + l accumulate + P pack
            float p[8];
#pragma unroll
            for (int ks = 0; ks < 2; ++ks)
#pragma unroll
                for (int r = 0; r < 4; ++r) {
                    const float e = __expf(sacc[ks][r] - SUBC);
                    p[ks * 4 + r] = e;
                    lreg += e;
                }
#pragma unroll
            for (int ks = 0; ks < 2; ++ks)
#pragma unroll
                for (int r2 = 0; r2 < 2; ++r2) {
                    const unsigned w = (unsigned)f2bfbits(p[ks * 4 + r2 * 2]) |
                                       ((unsigned)f2bfbits(p[ks * 4 + r2 * 2 + 1]) << 16);
                    const int byt = (ks * 32 + G * 8 + r2 * 4) ^ swq;
                    *(unsigned*)(pP + lq * 64 + byt) = w;
                }

            // PV: y^T += g^T * P^T
            const bf16x8 pf = *(const bf16x8*)(pP + lq * 64 + ((G * 16) ^ swq));
#pragma unroll
            for (int c = 0; c < 8; ++c) {
                const int row = c * 16 + lq;
                const bf16x8 gf = *(const bf16x8*)(gbuf + row * 128 + t2 * 64 +
                                                   ((G * 16) ^ ((row & 3) << 4)));
                yacc[c] = __builtin_amdgcn_mfma_f32_16x16x32_bf16(gf, pf, yacc[c], 0, 0, 0);
            }
        }
        __syncthreads();
    }

    // l reduce across the 4 G-groups (disjoint key subsets)
    lreg += __shfl_xor(lreg, 16);
    lreg += __shfl_xor(lreg, 32);

    const int sb = b * NSPLIT + s;
    if (lane < 16) lbuf[(size_t)sb * NN + qbase + lq] = lreg;
    // yp [sb][n][ci] bf16 (unnormalized)
    const size_t nrow = ((size_t)sb * NN + qbase + lq) * CI;
#pragma unroll
    for (int c = 0; c < 8; ++c) {
        unsigned short pkk[4];
#pragma unroll
        for (int r = 0; r < 4; ++r) pkk[r] = f2bfbits(yacc[c][r]);
        *(uint2*)&yp[nrow + c * 16 + G * 4] = *(uint2*)pkk;
    }
}

// ---------------------------------------------------------------------------
// K2b: combine 2 K-splits -> yT bf16 [b][n][ci].  grid (1024), 256 thr
// ---------------------------------------------------------------------------
__global__ __launch_bounds__(256) void k_combine(
    const unsigned short* __restrict__ yp,
    const float* __restrict__ lbuf,
    unsigned short* __restrict__ yT)
{
    const int idx = blockIdx.x * 256 + threadIdx.x;   // 262144 total
    const int ng = idx >> 4, u = idx & 15;
    const int b = ng >> 13, n = ng & 8191;
    const float l = lbuf[(size_t)(b * NSPLIT) * NN + n] +
                    lbuf[(size_t)(b * NSPLIT + 1) * NN + n];
    const float inv = 1.f / l;
    const uint4 u0 = *(const uint4*)&yp[((size_t)(b * NSPLIT) * NN + n) * CI + u * 8];
    const uint4 u1 = *(const uint4*)&yp[((size_t)(b * NSPLIT + 1) * NN + n) * CI + u * 8];
    const unsigned* a0 = (const unsigned*)&u0;
    const unsigned* a1 = (const unsigned*)&u1;
    unsigned short r[8];
#pragma unroll
    for (int j = 0; j < 4; ++j) {
        const float lo = bf2f((unsigned short)(a0[j] & 0xffff)) + bf2f((unsigned short)(a1[j] & 0xffff));
        const float hi = bf2f((unsigned short)(a0[j] >> 16))    + bf2f((unsigned short)(a1[j] >> 16));
        r[j * 2]     = f2bfbits(lo * inv);
        r[j * 2 + 1] = f2bfbits(hi * inv);
    }
    *(uint4*)&yT[((size_t)b * NN + n) * CI + u * 8] = *(uint4*)r;
}

// ---------------------------------------------------------------------------
// K3: output conv via bf16 MFMA split-W (128->256) + BN partial sums
// grid (128 nt of 64 n, 2 cot, 2 b), 256 thr = 4 waves (32 co each)
// ---------------------------------------------------------------------------
__global__ __launch_bounds__(256) void k_outconv(
    const unsigned short* __restrict__ yT,
    const unsigned short* __restrict__ woh, const unsigned short* __restrict__ wol,
    const float* __restrict__ obias, float* __restrict__ y2,
    float* __restrict__ psum, float* __restrict__ psq)
{
    const int nt_ = blockIdx.x, cot = blockIdx.y, b = blockIdx.z;
    const int nb = nt_ * 64;
    const int tid = threadIdx.x, wave = tid >> 6, lane = tid & 63;
    const int lq = lane & 15, G = lane >> 4;
    const int corow = cot * 128 + wave * 32;

    f32x4 acc[2][4];
#pragma unroll
    for (int ot = 0; ot < 2; ++ot)
#pragma unroll
        for (int nt = 0; nt < 4; ++nt) acc[ot][nt] = (f32x4){0.f, 0.f, 0.f, 0.f};

    const unsigned short* xrow = yT + ((size_t)b * NN + nb) * CI;
#pragma unroll
    for (int kc = 0; kc < 4; ++kc) {
        bf16x8 wh[2], wl[2], xf[4];
#pragma unroll
        for (int ot = 0; ot < 2; ++ot) {
            const size_t wr = (size_t)(corow + ot * 16 + lq) * CI + kc * 32 + G * 8;
            wh[ot] = *(const bf16x8*)(woh + wr);
            wl[ot] = *(const bf16x8*)(wol + wr);
        }
#pragma unroll
        for (int nt = 0; nt < 4; ++nt)
            xf[nt] = *(const bf16x8*)(xrow + (size_t)(nt * 16 + lq) * CI + kc * 32 + G * 8);
#pragma unroll
        for (int ot = 0; ot < 2; ++ot)
#pragma unroll
            for (int nt = 0; nt < 4; ++nt) {
                acc[ot][nt] = __builtin_amdgcn_mfma_f32_16x16x32_bf16(wh[ot], xf[nt], acc[ot][nt], 0, 0, 0);
                acc[ot][nt] = __builtin_amdgcn_mfma_f32_16x16x32_bf16(wl[ot], xf[nt], acc[ot][nt], 0, 0, 0);
            }
    }

#pragma unroll
    for (int ot = 0; ot < 2; ++ot) {
        const float4 bv = *(const float4*)&obias[corow + ot * 16 + G * 4];
#pragma unroll
        for (int nt = 0; nt < 4; ++nt) {
            acc[ot][nt][0] += bv.x; acc[ot][nt][1] += bv.y;
            acc[ot][nt][2] += bv.z; acc[ot][nt][3] += bv.w;
        }
    }

    // y2 [b][co][n] fp32
#pragma unroll
    for (int ot = 0; ot < 2; ++ot)
#pragma unroll
        for (int r = 0; r < 4; ++r) {
            const int co = corow + ot * 16 + G * 4 + r;
            float* dst = &y2[((size_t)b * CC + co) * NN + nb + lq];
#pragma unroll
            for (int nt = 0; nt < 4; ++nt) dst[nt * 16] = acc[ot][nt][r];
        }

    // BN partials: reduce over this block's 64 n
#pragma unroll
    for (int ot = 0; ot < 2; ++ot)
#pragma unroll
        for (int r = 0; r < 4; ++r) {
            float sv = 0.f, q = 0.f;
#pragma unroll
            for (int nt = 0; nt < 4; ++nt) {
                const float v = acc[ot][nt][r];
                sv += v; q += v * v;
            }
#pragma unroll
            for (int d = 1; d < 16; d <<= 1) { sv += __shfl_xor(sv, d); q += __shfl_xor(q, d); }
            if (lq == 0) {
                const int co = corow + ot * 16 + G * 4 + r;
                psum[co * 256 + b * 128 + nt_] = sv;
                psq [co * 256 + b * 128 + nt_] = q;
            }
        }
}

// K4: reduce partials -> mean, inv_std
__global__ void k_red(const float* __restrict__ psum, const float* __restrict__ psq,
                      float* __restrict__ stats)
{
    const int co = threadIdx.x;
    float s = 0.f, q = 0.f;
    for (int i = 0; i < 256; ++i) { s += psum[co * 256 + i]; q += psq[co * 256 + i]; }
    const float mean = s * (1.f / 16384.f);
    const float var = q * (1.f / 16384.f) - mean * mean;
    stats[co] = mean;
    stats[256 + co] = rsqrtf(var + 1e-5f);
}

// K5: out = x + bn(y2) ; y2 lives in d_out, in-place
__global__ __launch_bounds__(256) void k_bn(
    const float* __restrict__ x, const float* __restrict__ bw,
    const float* __restrict__ bb, const float* __restrict__ stats,
    float* __restrict__ out)
{
    const int i4 = blockIdx.x * 256 + threadIdx.x;
    const int c = (i4 >> 11) & 255;
    const float a = stats[256 + c] * bw[c];
    const float bias2 = bb[c] - stats[c] * a;
    const float4 v = ((const float4*)out)[i4];
    const float4 xv = ((const float4*)x)[i4];
    float4 r;
    r.x = xv.x + v.x * a + bias2;
    r.y = xv.y + v.y * a + bias2;
    r.z = xv.z + v.z * a + bias2;
    r.w = xv.w + v.w * a + bias2;
    ((float4*)out)[i4] = r;
}

extern "C" void kernel_launch(void* const* d_in, const int* in_sizes, int n_in,
                              void* d_out, int out_size, void* d_ws, size_t ws_size,
                              hipStream_t stream) {
    const float* x       = (const float*)d_in[0];
    const float* g_w     = (const float*)d_in[1];
    const float* g_b     = (const float*)d_in[2];
    const float* theta_w = (const float*)d_in[3];
    const float* theta_b = (const float*)d_in[4];
    const float* phi_w   = (const float*)d_in[5];
    const float* phi_b   = (const float*)d_in[6];
    const float* out_w   = (const float*)d_in[7];
    const float* out_b   = (const float*)d_in[8];
    const float* bn_w    = (const float*)d_in[9];
    const float* bn_b    = (const float*)d_in[10];

    char* ws = (char*)d_ws;
    unsigned short* xT      = (unsigned short*)(ws + OFF_XT);
    unsigned short* wqh     = (unsigned short*)(ws + OFF_WQH);
    unsigned short* wql     = (unsigned short*)(ws + OFF_WQL);
    unsigned short* woh     = (unsigned short*)(ws + OFF_WOH);
    unsigned short* wol     = (unsigned short*)(ws + OFF_WOL);
    unsigned short* theta16 = (unsigned short*)(ws + OFF_THETA16);
    unsigned short* phi16   = (unsigned short*)(ws + OFF_PHI16);
    unsigned short* g16     = (unsigned short*)(ws + OFF_G16);
    unsigned short* yT16    = (unsigned short*)(ws + OFF_YT16);
    unsigned short* yp      = (unsigned short*)(ws + OFF_YP);
    float* lbuf  = (float*)(ws + OFF_LBUF);
    float* psum  = (float*)(ws + OFF_PSUM);
    float* psq   = (float*)(ws + OFF_PSQ);
    float* stats = (float*)(ws + OFF_STAT);
    float* out   = (float*)d_out;

    k_prep<<<dim3(512), 256, 0, stream>>>(theta_w, phi_w, g_w, out_w, wqh, wql, woh, wol);
    k_xt<<<dim3(128, 4, 2), 256, 0, stream>>>(x, xT);
    k_qkvm<<<dim3(128, 3, 2), 256, 0, stream>>>(xT, wqh, wql, theta_b, phi_b, g_b,
                                                theta16, phi16, g16);
    k_attn<<<dim3(64, NSPLIT, 2), 512, 0, stream>>>(theta16, phi16, g16, yp, lbuf);
    k_combine<<<dim3(1024), 256, 0, stream>>>(yp, lbuf, yT16);
    k_outconv<<<dim3(128, 2, 2), 256, 0, stream>>>(yT16, woh, wol, out_b, out, psum, psq);
    k_red<<<1, 256, 0, stream>>>(psum, psq, stats);
    k_bn<<<4096, 256, 0, stream>>>(x, bn_w, bn_b, stats, out);
}